// Round 1
// baseline (752.724 us; speedup 1.0000x reference)
//
#include <hip/hip_runtime.h>

#define HIDDEN 128

// ---------------------------------------------------------------------------
// CSR build kernels
// ---------------------------------------------------------------------------
__global__ void zero_ints(int* __restrict__ a, int n) {
    int i = blockIdx.x * 256 + threadIdx.x;
    if (i < n) a[i] = 0;
}

__global__ void count_deg(const int* __restrict__ dst, int* __restrict__ deg, int e) {
    int i = blockIdx.x * 256 + threadIdx.x;
    if (i < e) atomicAdd(&deg[dst[i]], 1);
}

// phase 1: per-block (1024 items) partial sums
__global__ void scan_partial(const int* __restrict__ deg, int* __restrict__ bsum, int n) {
    __shared__ int sd[256];
    const int t = threadIdx.x;
    const int base = blockIdx.x * 1024;
    int s = 0;
    #pragma unroll
    for (int i = 0; i < 4; ++i) {
        int idx = base + t * 4 + i;
        if (idx < n) s += deg[idx];
    }
    sd[t] = s;
    __syncthreads();
    for (int o = 128; o > 0; o >>= 1) {
        if (t < o) sd[t] += sd[t + o];
        __syncthreads();
    }
    if (t == 0) bsum[blockIdx.x] = sd[0];
}

// phase 2: exclusive scan of block sums (nb <= 256), single block
__global__ void scan_bsum(int* __restrict__ bsum, int nb) {
    __shared__ int sd[256];
    const int t = threadIdx.x;
    int v = (t < nb) ? bsum[t] : 0;
    sd[t] = v;
    __syncthreads();
    for (int o = 1; o < 256; o <<= 1) {
        int add = (t >= o) ? sd[t - o] : 0;
        __syncthreads();
        sd[t] += add;
        __syncthreads();
    }
    if (t < nb) bsum[t] = sd[t] - v;   // exclusive
}

// phase 3: per-block exclusive scan + block offset -> node offsets
__global__ void scan_offsets(const int* __restrict__ deg, const int* __restrict__ bsum,
                             int* __restrict__ offs, int n) {
    __shared__ int sd[256];
    const int t = threadIdx.x;
    const int base = blockIdx.x * 1024;
    int v[4];
    int s = 0;
    #pragma unroll
    for (int i = 0; i < 4; ++i) {
        int idx = base + t * 4 + i;
        v[i] = (idx < n) ? deg[idx] : 0;
        s += v[i];
    }
    sd[t] = s;
    __syncthreads();
    const int mine = s;
    for (int o = 1; o < 256; o <<= 1) {
        int add = (t >= o) ? sd[t - o] : 0;
        __syncthreads();
        sd[t] += add;
        __syncthreads();
    }
    int excl = sd[t] - mine + bsum[blockIdx.x];
    #pragma unroll
    for (int i = 0; i < 4; ++i) {
        int idx = base + t * 4 + i;
        if (idx < n) { offs[idx] = excl; excl += v[i]; }
    }
}

__global__ void fill_csr(const int* __restrict__ src, const int* __restrict__ dst,
                         const int* __restrict__ offs, int* __restrict__ cnt,
                         int* __restrict__ csr, int e) {
    int i = blockIdx.x * 256 + threadIdx.x;
    if (i < e) {
        int d = dst[i];
        int p = offs[d] + atomicAdd(&cnt[d], 1);
        csr[p] = src[i];
    }
}

// ---------------------------------------------------------------------------
// Neighbor mean aggregation: one wave per node, lane owns 2 feature cols
// ---------------------------------------------------------------------------
__global__ void aggregate(const float* __restrict__ h, const int* __restrict__ offs,
                          const int* __restrict__ deg, const int* __restrict__ csr,
                          float* __restrict__ agg, int n) {
    int node = blockIdx.x * (blockDim.x >> 6) + (threadIdx.x >> 6);
    if (node >= n) return;
    const int lane = threadIdx.x & 63;
    const int start = offs[node];
    const int d = deg[node];
    float ax = 0.f, ay = 0.f;
    int i = 0;
    for (; i + 1 < d; i += 2) {
        int s0 = csr[start + i];
        int s1 = csr[start + i + 1];
        float2 v0 = *(const float2*)&h[s0 * HIDDEN + lane * 2];
        float2 v1 = *(const float2*)&h[s1 * HIDDEN + lane * 2];
        ax += v0.x + v1.x;
        ay += v0.y + v1.y;
    }
    if (i < d) {
        int s0 = csr[start + i];
        float2 v0 = *(const float2*)&h[s0 * HIDDEN + lane * 2];
        ax += v0.x;
        ay += v0.y;
    }
    const float inv = 1.0f / (float)max(d, 1);
    float2 o;
    o.x = ax * inv;
    o.y = ay * inv;
    *(float2*)&agg[node * HIDDEN + lane * 2] = o;
}

// ---------------------------------------------------------------------------
// Fused GEMM: out[r][c] = act( A[r]@W1 (+ B[r]@W2) + bias )[c],  c in [0,128)
// 128-row tile / block, 256 threads, K staged in 32-wide LDS tiles.
// ---------------------------------------------------------------------------
template <int K1, bool HAS_B, bool RELU>
__launch_bounds__(256, 2)
__global__ void gemm_fused(const float* __restrict__ A, const float* __restrict__ Bm,
                           const float* __restrict__ W1, const float* __restrict__ W2,
                           const float* __restrict__ bias, float* __restrict__ out,
                           int nrows) {
    constexpr int KT = 32;
    constexpr int ROWS = 128;
    constexpr int AST = KT + 4;   // padded stride: kills staging bank conflicts
    __shared__ float As[ROWS][AST];
    __shared__ float Bs[HAS_B ? ROWS : 1][AST];
    __shared__ float W1s[KT][HIDDEN];
    __shared__ float W2s[HAS_B ? KT : 1][HIDDEN];

    const int t = threadIdx.x;
    const int lane = t & 63;
    const int wave = t >> 6;
    const int rh = lane >> 5;              // which 16-row half of the wave's band
    const int c0 = (lane & 31) * 4;        // 4 output cols per lane
    const int rowBase = wave * 32 + rh * 16;
    const int blockRow0 = blockIdx.x * ROWS;
    const int nbr = min(ROWS, nrows - blockRow0);

    float acc[16][4];
    #pragma unroll
    for (int j = 0; j < 16; ++j)
        #pragma unroll
        for (int c = 0; c < 4; ++c) acc[j][c] = 0.f;

    #pragma unroll 1
    for (int kt = 0; kt < K1; kt += KT) {
        // stage A (and B): 128 rows x 32 floats = 1024 float4
        #pragma unroll
        for (int i = 0; i < 4; ++i) {
            int flat = t + i * 256;
            int r = flat >> 3;
            int kk = (flat & 7) << 2;
            float4 va = make_float4(0.f, 0.f, 0.f, 0.f);
            if (r < nbr) va = *(const float4*)&A[(blockRow0 + r) * K1 + kt + kk];
            *(float4*)&As[r][kk] = va;
            if (HAS_B) {
                float4 vb = make_float4(0.f, 0.f, 0.f, 0.f);
                if (r < nbr) vb = *(const float4*)&Bm[(blockRow0 + r) * K1 + kt + kk];
                *(float4*)&Bs[r][kk] = vb;
            }
        }
        // stage W tiles: 32 x 128 floats = 1024 float4 each
        #pragma unroll
        for (int i = 0; i < 4; ++i) {
            int flat = t + i * 256;
            int k = flat >> 5;
            int c4 = (flat & 31) << 2;
            *(float4*)&W1s[k][c4] = *(const float4*)&W1[(kt + k) * HIDDEN + c4];
            if (HAS_B)
                *(float4*)&W2s[k][c4] = *(const float4*)&W2[(kt + k) * HIDDEN + c4];
        }
        __syncthreads();

        #pragma unroll 1
        for (int k = 0; k < KT; k += 4) {
            float4 w1[4];
            #pragma unroll
            for (int kk = 0; kk < 4; ++kk) w1[kk] = *(const float4*)&W1s[k + kk][c0];
            float4 w2[4];
            if (HAS_B) {
                #pragma unroll
                for (int kk = 0; kk < 4; ++kk) w2[kk] = *(const float4*)&W2s[k + kk][c0];
            }
            #pragma unroll
            for (int j = 0; j < 16; ++j) {
                const int r = rowBase + j;
                float4 a = *(const float4*)&As[r][k];
                float av[4] = {a.x, a.y, a.z, a.w};
                #pragma unroll
                for (int kk = 0; kk < 4; ++kk) {
                    acc[j][0] = fmaf(av[kk], w1[kk].x, acc[j][0]);
                    acc[j][1] = fmaf(av[kk], w1[kk].y, acc[j][1]);
                    acc[j][2] = fmaf(av[kk], w1[kk].z, acc[j][2]);
                    acc[j][3] = fmaf(av[kk], w1[kk].w, acc[j][3]);
                }
                if (HAS_B) {
                    float4 b = *(const float4*)&Bs[r][k];
                    float bv[4] = {b.x, b.y, b.z, b.w};
                    #pragma unroll
                    for (int kk = 0; kk < 4; ++kk) {
                        acc[j][0] = fmaf(bv[kk], w2[kk].x, acc[j][0]);
                        acc[j][1] = fmaf(bv[kk], w2[kk].y, acc[j][1]);
                        acc[j][2] = fmaf(bv[kk], w2[kk].z, acc[j][2]);
                        acc[j][3] = fmaf(bv[kk], w2[kk].w, acc[j][3]);
                    }
                }
            }
        }
        __syncthreads();
    }

    const float4 bv4 = *(const float4*)&bias[c0];
    #pragma unroll
    for (int j = 0; j < 16; ++j) {
        int r = rowBase + j;
        if (r < nbr) {
            float4 o;
            o.x = acc[j][0] + bv4.x;
            o.y = acc[j][1] + bv4.y;
            o.z = acc[j][2] + bv4.z;
            o.w = acc[j][3] + bv4.w;
            if (RELU) {
                o.x = fmaxf(o.x, 0.f);
                o.y = fmaxf(o.y, 0.f);
                o.z = fmaxf(o.z, 0.f);
                o.w = fmaxf(o.w, 0.f);
            }
            *(float4*)&out[(blockRow0 + r) * HIDDEN + c0] = o;
        }
    }
}

// ---------------------------------------------------------------------------
// Final projection: out[r] = dot(h[r], W_fin). One wave per row.
// ---------------------------------------------------------------------------
__global__ void final_dot(const float* __restrict__ h, const float* __restrict__ wfin,
                          float* __restrict__ out, int n) {
    int node = blockIdx.x * (blockDim.x >> 6) + (threadIdx.x >> 6);
    if (node >= n) return;
    const int lane = threadIdx.x & 63;
    float2 v = *(const float2*)&h[node * HIDDEN + lane * 2];
    float2 w = *(const float2*)&wfin[lane * 2];
    float s = v.x * w.x + v.y * w.y;
    #pragma unroll
    for (int o = 32; o > 0; o >>= 1) s += __shfl_down(s, o, 64);
    if (lane == 0) out[node] = s;
}

// ---------------------------------------------------------------------------
extern "C" void kernel_launch(void* const* d_in, const int* in_sizes, int n_in,
                              void* d_out, int out_size, void* d_ws, size_t ws_size,
                              hipStream_t stream) {
    const float* x     = (const float*)d_in[0];
    const float* W_t   = (const float*)d_in[1];
    const float* b_t   = (const float*)d_in[2];
    const float* W_s0  = (const float*)d_in[3];
    const float* b_s0  = (const float*)d_in[4];
    const float* W_n0  = (const float*)d_in[5];
    const float* W_s1  = (const float*)d_in[6];
    const float* b_s1  = (const float*)d_in[7];
    const float* W_n1  = (const float*)d_in[8];
    const float* W_fin = (const float*)d_in[9];
    const int*   src   = (const int*)d_in[10];
    const int*   dst   = (const int*)d_in[11];
    float* out = (float*)d_out;

    const int N = in_sizes[0] / 256;   // 100000
    const int E = in_sizes[10];        // 1600000

    // workspace carving (256B aligned)
    size_t off_b = 0;
    auto carve = [&](size_t bytes) {
        size_t cur = off_b;
        off_b = (off_b + bytes + 255) & ~(size_t)255;
        return cur;
    };
    char* base = (char*)d_ws;
    int* deg  = (int*)(base + carve((size_t)(2 * N) * 4));  // deg + cnt adjacent
    int* cnt  = deg + N;
    int* offs = (int*)(base + carve((size_t)N * 4));
    int* bsum = (int*)(base + carve(1024 * 4));
    int* csr  = (int*)(base + carve((size_t)E * 4));
    float* hA  = (float*)(base + carve((size_t)N * HIDDEN * 4));
    float* hB  = (float*)(base + carve((size_t)N * HIDDEN * 4));
    float* agg = (float*)(base + carve((size_t)N * HIDDEN * 4));
    (void)ws_size; (void)n_in; (void)out_size;

    const int nbScan = (N + 1023) / 1024;   // 98 (<=256 required by scan_bsum)

    // --- CSR build ---
    hipLaunchKernelGGL(zero_ints, dim3((2 * N + 255) / 256), dim3(256), 0, stream, deg, 2 * N);
    hipLaunchKernelGGL(count_deg, dim3((E + 255) / 256), dim3(256), 0, stream, dst, deg, E);
    hipLaunchKernelGGL(scan_partial, dim3(nbScan), dim3(256), 0, stream, deg, bsum, N);
    hipLaunchKernelGGL(scan_bsum, dim3(1), dim3(256), 0, stream, bsum, nbScan);
    hipLaunchKernelGGL(scan_offsets, dim3(nbScan), dim3(256), 0, stream, deg, bsum, offs, N);
    hipLaunchKernelGGL(fill_csr, dim3((E + 255) / 256), dim3(256), 0, stream, src, dst, offs, cnt, csr, E);

    const int gemmGrid = (N + 127) / 128;
    const int aggGrid = (N + 3) / 4;

    // h = x @ W_t + b_t
    hipLaunchKernelGGL((gemm_fused<256, false, false>), dim3(gemmGrid), dim3(256), 0, stream,
                       x, (const float*)nullptr, W_t, (const float*)nullptr, b_t, hA, N);
    // layer 0
    hipLaunchKernelGGL(aggregate, dim3(aggGrid), dim3(256), 0, stream, hA, offs, deg, csr, agg, N);
    hipLaunchKernelGGL((gemm_fused<128, true, true>), dim3(gemmGrid), dim3(256), 0, stream,
                       hA, agg, W_s0, W_n0, b_s0, hB, N);
    // layer 1
    hipLaunchKernelGGL(aggregate, dim3(aggGrid), dim3(256), 0, stream, hB, offs, deg, csr, agg, N);
    hipLaunchKernelGGL((gemm_fused<128, true, true>), dim3(gemmGrid), dim3(256), 0, stream,
                       hB, agg, W_s1, W_n1, b_s1, hA, N);
    // final projection
    hipLaunchKernelGGL(final_dot, dim3(aggGrid), dim3(256), 0, stream, hA, W_fin, out, N);
}

// Round 2
// 580.335 us; speedup vs baseline: 1.2971x; 1.2971x over previous
//
#include <hip/hip_runtime.h>

#define HIDDEN 128

using short8 = __attribute__((ext_vector_type(8))) short;
using f32x4  = __attribute__((ext_vector_type(4))) float;

// ---------------------------------------------------------------------------
// bf16 split helpers (RNE)
// ---------------------------------------------------------------------------
__device__ __forceinline__ unsigned short f2bf(float f) {
    unsigned u = __float_as_uint(f);
    return (unsigned short)((u + 0x7fffu + ((u >> 16) & 1u)) >> 16);
}
__device__ __forceinline__ float bf2f(unsigned short h) {
    return __uint_as_float(((unsigned)h) << 16);
}

__device__ __forceinline__ void gload16(const void* g, void* l) {
    __builtin_amdgcn_global_load_lds((const __attribute__((address_space(1))) void*)g,
                                     (__attribute__((address_space(3))) void*)l,
                                     16, 0, 0);
}

// ---------------------------------------------------------------------------
// CSR build kernels (unchanged from R1)
// ---------------------------------------------------------------------------
__global__ void zero_ints(int* __restrict__ a, int n) {
    int i = blockIdx.x * 256 + threadIdx.x;
    if (i < n) a[i] = 0;
}

__global__ void count_deg(const int* __restrict__ dst, int* __restrict__ deg, int e) {
    int i = blockIdx.x * 256 + threadIdx.x;
    if (i < e) atomicAdd(&deg[dst[i]], 1);
}

__global__ void scan_partial(const int* __restrict__ deg, int* __restrict__ bsum, int n) {
    __shared__ int sd[256];
    const int t = threadIdx.x;
    const int base = blockIdx.x * 1024;
    int s = 0;
    #pragma unroll
    for (int i = 0; i < 4; ++i) {
        int idx = base + t * 4 + i;
        if (idx < n) s += deg[idx];
    }
    sd[t] = s;
    __syncthreads();
    for (int o = 128; o > 0; o >>= 1) {
        if (t < o) sd[t] += sd[t + o];
        __syncthreads();
    }
    if (t == 0) bsum[blockIdx.x] = sd[0];
}

__global__ void scan_bsum(int* __restrict__ bsum, int nb) {
    __shared__ int sd[256];
    const int t = threadIdx.x;
    int v = (t < nb) ? bsum[t] : 0;
    sd[t] = v;
    __syncthreads();
    for (int o = 1; o < 256; o <<= 1) {
        int add = (t >= o) ? sd[t - o] : 0;
        __syncthreads();
        sd[t] += add;
        __syncthreads();
    }
    if (t < nb) bsum[t] = sd[t] - v;
}

__global__ void scan_offsets(const int* __restrict__ deg, const int* __restrict__ bsum,
                             int* __restrict__ offs, int n) {
    __shared__ int sd[256];
    const int t = threadIdx.x;
    const int base = blockIdx.x * 1024;
    int v[4];
    int s = 0;
    #pragma unroll
    for (int i = 0; i < 4; ++i) {
        int idx = base + t * 4 + i;
        v[i] = (idx < n) ? deg[idx] : 0;
        s += v[i];
    }
    sd[t] = s;
    __syncthreads();
    const int mine = s;
    for (int o = 1; o < 256; o <<= 1) {
        int add = (t >= o) ? sd[t - o] : 0;
        __syncthreads();
        sd[t] += add;
        __syncthreads();
    }
    int excl = sd[t] - mine + bsum[blockIdx.x];
    #pragma unroll
    for (int i = 0; i < 4; ++i) {
        int idx = base + t * 4 + i;
        if (idx < n) { offs[idx] = excl; excl += v[i]; }
    }
}

__global__ void fill_csr(const int* __restrict__ src, const int* __restrict__ dst,
                         const int* __restrict__ offs, int* __restrict__ cnt,
                         int* __restrict__ csr, int e) {
    int i = blockIdx.x * 256 + threadIdx.x;
    if (i < e) {
        int d = dst[i];
        int p = offs[d] + atomicAdd(&cnt[d], 1);
        csr[p] = src[i];
    }
}

// ---------------------------------------------------------------------------
// Pack weights into MFMA-fragment-ordered split-bf16 planes.
// Layout per weight: [hi plane | lo plane]; plane = [K/32 steps][8 ct][64 lane][8 bf16]
// where lane l supplies col = ct*16 + (l&15), k = step*32 + (l>>4)*8 + j.
// ---------------------------------------------------------------------------
__global__ void pack_weights(const float* __restrict__ W_t, const float* __restrict__ Ws0,
                             const float* __restrict__ Wn0, const float* __restrict__ Ws1,
                             const float* __restrict__ Wn1,
                             unsigned short* p_t, unsigned short* p_s0, unsigned short* p_n0,
                             unsigned short* p_s1, unsigned short* p_n1) {
    const int bid = blockIdx.x;
    const float* W; unsigned short* out; int K; int b0;
    if (bid < 16)      { W = W_t; out = p_t;  K = 256; b0 = 0;  }
    else if (bid < 24) { W = Ws0; out = p_s0; K = 128; b0 = 16; }
    else if (bid < 32) { W = Wn0; out = p_n0; K = 128; b0 = 24; }
    else if (bid < 40) { W = Ws1; out = p_s1; K = 128; b0 = 32; }
    else               { W = Wn1; out = p_n1; K = 128; b0 = 40; }
    const int idx = (bid - b0) * 256 + threadIdx.x;   // < K*16
    const int step = idx >> 9;
    const int r = idx & 511;
    const int ct = r >> 6, l = r & 63;
    const int col = ct * 16 + (l & 15);
    const int k0 = step * 32 + ((l >> 4) << 3);
    const int planeElems = K * HIDDEN;
    #pragma unroll
    for (int j = 0; j < 8; ++j) {
        float f = W[(k0 + j) * HIDDEN + col];
        unsigned short h = f2bf(f);
        out[idx * 8 + j] = h;
        out[planeElems + idx * 8 + j] = f2bf(f - bf2f(h));
    }
}

// ---------------------------------------------------------------------------
// MFMA GEMM with f32 emulation via split bf16 (4 products hh+lh+hl+ll).
// out[r][c] = act( sum_m A_m[r] @ W_m + bias )[c], c in [0,128).
// Block: 128 rows x 128 cols, 4 waves (2x2), wave tile 64x64, K-step 32.
// A inputs: F32A ? raw f32 matrix (reg-staged + split) : split-bf16 planes.
// ---------------------------------------------------------------------------
template <int KIN, int NIN, bool RELU, bool F32A>
__launch_bounds__(256, 2)
__global__ void gemm_mfma(const void* __restrict__ A0, const void* __restrict__ A1,
                          const unsigned short* __restrict__ Wp0,
                          const unsigned short* __restrict__ Wp1,
                          const float* __restrict__ bias,
                          unsigned short* __restrict__ outsplit, int nrows) {
    __shared__ __align__(16) unsigned short Ahi[8][64][8];   // 8 KB each
    __shared__ __align__(16) unsigned short Alo[8][64][8];
    __shared__ __align__(16) unsigned short Bhi[8][64][8];
    __shared__ __align__(16) unsigned short Blo[8][64][8];

    const int t = threadIdx.x;
    const int lane = t & 63;
    const int w = t >> 6;
    const int wr = w >> 1, wc = w & 1;
    const int blockRow0 = blockIdx.x * 128;

    f32x4 acc[4][4];
    #pragma unroll
    for (int i = 0; i < 4; ++i)
        #pragma unroll
        for (int j = 0; j < 4; ++j) acc[i][j] = (f32x4){0.f, 0.f, 0.f, 0.f};

    #pragma unroll 1
    for (int m = 0; m < NIN; ++m) {
        const unsigned short* Wp = m ? Wp1 : Wp0;
        const void* Am = m ? A1 : A0;
        #pragma unroll 1
        for (int kt = 0; kt < KIN; kt += 32) {
            const int step = kt >> 5;
            // --- stage W (both planes): 2 ct per wave, fragment-linear copy ---
            {
                const unsigned short* WpH = Wp + (size_t)step * 4096;
                const unsigned short* WpL = WpH + (size_t)KIN * HIDDEN;
                #pragma unroll
                for (int i = 0; i < 2; ++i) {
                    const int ct = w * 2 + i;
                    gload16(WpH + ct * 512 + lane * 8, &Bhi[ct][0][0]);
                    gload16(WpL + ct * 512 + lane * 8, &Blo[ct][0][0]);
                }
            }
            // --- stage A in reader-fragment order ---
            if constexpr (F32A) {
                const float* X = (const float*)Am;
                #pragma unroll
                for (int u = 0; u < 2; ++u) {
                    const int c = t + u * 256;
                    const int rt = c >> 6, cl = c & 63;
                    int row = blockRow0 + rt * 16 + (cl & 15);
                    row = min(row, nrows - 1);
                    const int k = kt + ((cl >> 4) << 3);
                    const float* p = &X[(size_t)row * KIN + k];
                    float4 f0 = *(const float4*)p;
                    float4 f1 = *(const float4*)(p + 4);
                    float fv[8] = {f0.x, f0.y, f0.z, f0.w, f1.x, f1.y, f1.z, f1.w};
                    union { short8 v; unsigned short u16[8]; } vh, vl;
                    #pragma unroll
                    for (int j = 0; j < 8; ++j) {
                        unsigned short h = f2bf(fv[j]);
                        vh.u16[j] = h;
                        vl.u16[j] = f2bf(fv[j] - bf2f(h));
                    }
                    *(short8*)&Ahi[rt][cl][0] = vh.v;
                    *(short8*)&Alo[rt][cl][0] = vl.v;
                }
            } else {
                const unsigned short* Hh = (const unsigned short*)Am;
                const unsigned short* Hl = Hh + (size_t)nrows * HIDDEN;
                #pragma unroll
                for (int i = 0; i < 2; ++i) {
                    const int rt = w * 2 + i;
                    int row = blockRow0 + rt * 16 + (lane & 15);
                    row = min(row, nrows - 1);
                    const int k = kt + ((lane >> 4) << 3);
                    gload16(Hh + (size_t)row * HIDDEN + k, &Ahi[rt][0][0]);
                    gload16(Hl + (size_t)row * HIDDEN + k, &Alo[rt][0][0]);
                }
            }
            __syncthreads();
            // --- compute: 16 conflict-free ds_read_b128, 64 MFMA ---
            short8 bh[4], bl[4];
            #pragma unroll
            for (int c4 = 0; c4 < 4; ++c4) {
                bh[c4] = *(const short8*)&Bhi[wc * 4 + c4][lane][0];
                bl[c4] = *(const short8*)&Blo[wc * 4 + c4][lane][0];
            }
            #pragma unroll
            for (int r4 = 0; r4 < 4; ++r4) {
                short8 ah = *(const short8*)&Ahi[wr * 4 + r4][lane][0];
                short8 al = *(const short8*)&Alo[wr * 4 + r4][lane][0];
                #pragma unroll
                for (int c4 = 0; c4 < 4; ++c4) {
                    acc[r4][c4] = __builtin_amdgcn_mfma_f32_16x16x32_bf16(ah, bh[c4], acc[r4][c4], 0, 0, 0);
                    acc[r4][c4] = __builtin_amdgcn_mfma_f32_16x16x32_bf16(al, bh[c4], acc[r4][c4], 0, 0, 0);
                    acc[r4][c4] = __builtin_amdgcn_mfma_f32_16x16x32_bf16(ah, bl[c4], acc[r4][c4], 0, 0, 0);
                    acc[r4][c4] = __builtin_amdgcn_mfma_f32_16x16x32_bf16(al, bl[c4], acc[r4][c4], 0, 0, 0);
                }
            }
            __syncthreads();
        }
    }
    // --- epilogue: bias, relu, split-store ---
    unsigned short* outHi = outsplit;
    unsigned short* outLo = outsplit + (size_t)nrows * HIDDEN;
    #pragma unroll
    for (int c4 = 0; c4 < 4; ++c4) {
        const int col = (wc * 4 + c4) * 16 + (lane & 15);
        const float bc = bias[col];
        #pragma unroll
        for (int r4 = 0; r4 < 4; ++r4) {
            const int r0 = blockRow0 + (wr * 4 + r4) * 16 + ((lane >> 4) << 2);
            #pragma unroll
            for (int j = 0; j < 4; ++j) {
                const int r = r0 + j;
                if (r < nrows) {
                    float v = acc[r4][c4][j] + bc;
                    if (RELU) v = fmaxf(v, 0.f);
                    unsigned short h = f2bf(v);
                    outHi[(size_t)r * HIDDEN + col] = h;
                    outLo[(size_t)r * HIDDEN + col] = f2bf(v - bf2f(h));
                }
            }
        }
    }
}

// ---------------------------------------------------------------------------
// Neighbor mean over split-bf16 h (exact f32 reconstruct = hi + lo).
// One wave per node, lane owns 2 feature cols; 4-deep unroll for MLP.
// ---------------------------------------------------------------------------
__global__ void aggregate_split(const unsigned short* __restrict__ h, const int* __restrict__ offs,
                                const int* __restrict__ deg, const int* __restrict__ csr,
                                unsigned short* __restrict__ agg, int n) {
    const int node = blockIdx.x * 4 + (threadIdx.x >> 6);
    if (node >= n) return;
    const int lane = threadIdx.x & 63;
    const unsigned short* hi = h;
    const unsigned short* lo = h + (size_t)n * HIDDEN;
    const int start = offs[node];
    const int d = deg[node];
    float a0 = 0.f, a1 = 0.f;
    int i = 0;
    for (; i + 3 < d; i += 4) {
        int s0 = csr[start + i], s1 = csr[start + i + 1];
        int s2 = csr[start + i + 2], s3 = csr[start + i + 3];
        unsigned vh0 = *(const unsigned*)&hi[(size_t)s0 * HIDDEN + lane * 2];
        unsigned vl0 = *(const unsigned*)&lo[(size_t)s0 * HIDDEN + lane * 2];
        unsigned vh1 = *(const unsigned*)&hi[(size_t)s1 * HIDDEN + lane * 2];
        unsigned vl1 = *(const unsigned*)&lo[(size_t)s1 * HIDDEN + lane * 2];
        unsigned vh2 = *(const unsigned*)&hi[(size_t)s2 * HIDDEN + lane * 2];
        unsigned vl2 = *(const unsigned*)&lo[(size_t)s2 * HIDDEN + lane * 2];
        unsigned vh3 = *(const unsigned*)&hi[(size_t)s3 * HIDDEN + lane * 2];
        unsigned vl3 = *(const unsigned*)&lo[(size_t)s3 * HIDDEN + lane * 2];
        a0 += __uint_as_float(vh0 << 16) + __uint_as_float(vl0 << 16);
        a1 += __uint_as_float(vh0 & 0xffff0000u) + __uint_as_float(vl0 & 0xffff0000u);
        a0 += __uint_as_float(vh1 << 16) + __uint_as_float(vl1 << 16);
        a1 += __uint_as_float(vh1 & 0xffff0000u) + __uint_as_float(vl1 & 0xffff0000u);
        a0 += __uint_as_float(vh2 << 16) + __uint_as_float(vl2 << 16);
        a1 += __uint_as_float(vh2 & 0xffff0000u) + __uint_as_float(vl2 & 0xffff0000u);
        a0 += __uint_as_float(vh3 << 16) + __uint_as_float(vl3 << 16);
        a1 += __uint_as_float(vh3 & 0xffff0000u) + __uint_as_float(vl3 & 0xffff0000u);
    }
    for (; i < d; ++i) {
        int s0 = csr[start + i];
        unsigned vh0 = *(const unsigned*)&hi[(size_t)s0 * HIDDEN + lane * 2];
        unsigned vl0 = *(const unsigned*)&lo[(size_t)s0 * HIDDEN + lane * 2];
        a0 += __uint_as_float(vh0 << 16) + __uint_as_float(vl0 << 16);
        a1 += __uint_as_float(vh0 & 0xffff0000u) + __uint_as_float(vl0 & 0xffff0000u);
    }
    const float inv = 1.0f / (float)max(d, 1);
    const float m0 = a0 * inv, m1 = a1 * inv;
    unsigned short h0 = f2bf(m0), l0 = f2bf(m0 - bf2f(h0));
    unsigned short h1 = f2bf(m1), l1 = f2bf(m1 - bf2f(h1));
    unsigned short* aggHi = agg;
    unsigned short* aggLo = agg + (size_t)n * HIDDEN;
    *(unsigned*)&aggHi[(size_t)node * HIDDEN + lane * 2] = (unsigned)h0 | ((unsigned)h1 << 16);
    *(unsigned*)&aggLo[(size_t)node * HIDDEN + lane * 2] = (unsigned)l0 | ((unsigned)l1 << 16);
}

// ---------------------------------------------------------------------------
// Final projection from split h: out[r] = dot(h[r], W_fin). One wave per row.
// ---------------------------------------------------------------------------
__global__ void final_dot(const unsigned short* __restrict__ h, const float* __restrict__ wfin,
                          float* __restrict__ out, int n) {
    const int node = blockIdx.x * 4 + (threadIdx.x >> 6);
    if (node >= n) return;
    const int lane = threadIdx.x & 63;
    const unsigned short* hi = h;
    const unsigned short* lo = h + (size_t)n * HIDDEN;
    unsigned vh = *(const unsigned*)&hi[(size_t)node * HIDDEN + lane * 2];
    unsigned vl = *(const unsigned*)&lo[(size_t)node * HIDDEN + lane * 2];
    float v0 = __uint_as_float(vh << 16) + __uint_as_float(vl << 16);
    float v1 = __uint_as_float(vh & 0xffff0000u) + __uint_as_float(vl & 0xffff0000u);
    float2 wv = *(const float2*)&wfin[lane * 2];
    float s = v0 * wv.x + v1 * wv.y;
    #pragma unroll
    for (int o = 32; o > 0; o >>= 1) s += __shfl_down(s, o, 64);
    if (lane == 0) out[node] = s;
}

// ---------------------------------------------------------------------------
extern "C" void kernel_launch(void* const* d_in, const int* in_sizes, int n_in,
                              void* d_out, int out_size, void* d_ws, size_t ws_size,
                              hipStream_t stream) {
    const float* x     = (const float*)d_in[0];
    const float* W_t   = (const float*)d_in[1];
    const float* b_t   = (const float*)d_in[2];
    const float* W_s0  = (const float*)d_in[3];
    const float* b_s0  = (const float*)d_in[4];
    const float* W_n0  = (const float*)d_in[5];
    const float* W_s1  = (const float*)d_in[6];
    const float* b_s1  = (const float*)d_in[7];
    const float* W_n1  = (const float*)d_in[8];
    const float* W_fin = (const float*)d_in[9];
    const int*   src   = (const int*)d_in[10];
    const int*   dst   = (const int*)d_in[11];
    float* out = (float*)d_out;

    const int N = in_sizes[0] / 256;   // 100000
    const int E = in_sizes[10];        // 1600000

    // workspace carving (256B aligned)
    size_t off_b = 0;
    auto carve = [&](size_t bytes) {
        size_t cur = off_b;
        off_b = (off_b + bytes + 255) & ~(size_t)255;
        return cur;
    };
    char* base = (char*)d_ws;
    int* deg  = (int*)(base + carve((size_t)(2 * N) * 4));  // deg + cnt adjacent
    int* cnt  = deg + N;
    int* offs = (int*)(base + carve((size_t)N * 4));
    int* bsum = (int*)(base + carve(1024 * 4));
    int* csr  = (int*)(base + carve((size_t)E * 4));
    unsigned short* wp_t  = (unsigned short*)(base + carve((size_t)256 * HIDDEN * 2 * 2));
    unsigned short* wp_s0 = (unsigned short*)(base + carve((size_t)128 * HIDDEN * 2 * 2));
    unsigned short* wp_n0 = (unsigned short*)(base + carve((size_t)128 * HIDDEN * 2 * 2));
    unsigned short* wp_s1 = (unsigned short*)(base + carve((size_t)128 * HIDDEN * 2 * 2));
    unsigned short* wp_n1 = (unsigned short*)(base + carve((size_t)128 * HIDDEN * 2 * 2));
    unsigned short* hA   = (unsigned short*)(base + carve((size_t)N * HIDDEN * 2 * 2));
    unsigned short* hB   = (unsigned short*)(base + carve((size_t)N * HIDDEN * 2 * 2));
    unsigned short* aggP = (unsigned short*)(base + carve((size_t)N * HIDDEN * 2 * 2));
    (void)ws_size; (void)n_in; (void)out_size;

    const int nbScan = (N + 1023) / 1024;   // 98 (<=256 required by scan_bsum)

    // --- CSR build ---
    hipLaunchKernelGGL(zero_ints, dim3((2 * N + 255) / 256), dim3(256), 0, stream, deg, 2 * N);
    hipLaunchKernelGGL(count_deg, dim3((E + 255) / 256), dim3(256), 0, stream, dst, deg, E);
    hipLaunchKernelGGL(scan_partial, dim3(nbScan), dim3(256), 0, stream, deg, bsum, N);
    hipLaunchKernelGGL(scan_bsum, dim3(1), dim3(256), 0, stream, bsum, nbScan);
    hipLaunchKernelGGL(scan_offsets, dim3(nbScan), dim3(256), 0, stream, deg, bsum, offs, N);
    hipLaunchKernelGGL(fill_csr, dim3((E + 255) / 256), dim3(256), 0, stream, src, dst, offs, cnt, csr, E);

    // --- weight packing (48 tiny blocks) ---
    hipLaunchKernelGGL(pack_weights, dim3(48), dim3(256), 0, stream,
                       W_t, W_s0, W_n0, W_s1, W_n1, wp_t, wp_s0, wp_n0, wp_s1, wp_n1);

    const int gemmGrid = (N + 127) / 128;
    const int nodeGrid = (N + 3) / 4;

    // h0 = x @ W_t + b_t  (f32 A, reg-staged split)
    hipLaunchKernelGGL((gemm_mfma<256, 1, false, true>), dim3(gemmGrid), dim3(256), 0, stream,
                       (const void*)x, (const void*)nullptr, wp_t, (const unsigned short*)nullptr,
                       b_t, hA, N);
    // layer 0
    hipLaunchKernelGGL(aggregate_split, dim3(nodeGrid), dim3(256), 0, stream, hA, offs, deg, csr, aggP, N);
    hipLaunchKernelGGL((gemm_mfma<128, 2, true, false>), dim3(gemmGrid), dim3(256), 0, stream,
                       (const void*)hA, (const void*)aggP, wp_s0, wp_n0, b_s0, hB, N);
    // layer 1
    hipLaunchKernelGGL(aggregate_split, dim3(nodeGrid), dim3(256), 0, stream, hB, offs, deg, csr, aggP, N);
    hipLaunchKernelGGL((gemm_mfma<128, 2, true, false>), dim3(gemmGrid), dim3(256), 0, stream,
                       (const void*)hB, (const void*)aggP, wp_s1, wp_n1, b_s1, hA, N);
    // final projection
    hipLaunchKernelGGL(final_dot, dim3(nodeGrid), dim3(256), 0, stream, hA, W_fin, out, N);
}

// Round 3
// 568.093 us; speedup vs baseline: 1.3250x; 1.0215x over previous
//
#include <hip/hip_runtime.h>

#define HIDDEN 128

using short8 = __attribute__((ext_vector_type(8))) short;
using f32x4  = __attribute__((ext_vector_type(4))) float;

// ---------------------------------------------------------------------------
// bf16 split helpers (RNE)
// ---------------------------------------------------------------------------
__device__ __forceinline__ unsigned short f2bf(float f) {
    unsigned u = __float_as_uint(f);
    return (unsigned short)((u + 0x7fffu + ((u >> 16) & 1u)) >> 16);
}
__device__ __forceinline__ float bf2f(unsigned short h) {
    return __uint_as_float(((unsigned)h) << 16);
}

__device__ __forceinline__ void gload16(const void* g, void* l) {
    __builtin_amdgcn_global_load_lds((const __attribute__((address_space(1))) void*)g,
                                     (__attribute__((address_space(3))) void*)l,
                                     16, 0, 0);
}

// ---------------------------------------------------------------------------
// CSR build kernels
// ---------------------------------------------------------------------------
__global__ void zero_ints(int* __restrict__ a, int n) {
    int i = blockIdx.x * 256 + threadIdx.x;
    if (i < n) a[i] = 0;
}

__global__ void count_deg(const int* __restrict__ dst, int* __restrict__ deg, int e) {
    int i = blockIdx.x * 256 + threadIdx.x;
    if (i < e) atomicAdd(&deg[dst[i]], 1);
}

__global__ void scan_partial(const int* __restrict__ deg, int* __restrict__ bsum, int n) {
    __shared__ int sd[256];
    const int t = threadIdx.x;
    const int base = blockIdx.x * 1024;
    int s = 0;
    #pragma unroll
    for (int i = 0; i < 4; ++i) {
        int idx = base + t * 4 + i;
        if (idx < n) s += deg[idx];
    }
    sd[t] = s;
    __syncthreads();
    for (int o = 128; o > 0; o >>= 1) {
        if (t < o) sd[t] += sd[t + o];
        __syncthreads();
    }
    if (t == 0) bsum[blockIdx.x] = sd[0];
}

__global__ void scan_bsum(int* __restrict__ bsum, int nb) {
    __shared__ int sd[256];
    const int t = threadIdx.x;
    int v = (t < nb) ? bsum[t] : 0;
    sd[t] = v;
    __syncthreads();
    for (int o = 1; o < 256; o <<= 1) {
        int add = (t >= o) ? sd[t - o] : 0;
        __syncthreads();
        sd[t] += add;
        __syncthreads();
    }
    if (t < nb) bsum[t] = sd[t] - v;
}

__global__ void scan_offsets(const int* __restrict__ deg, const int* __restrict__ bsum,
                             int* __restrict__ offs, int n) {
    __shared__ int sd[256];
    const int t = threadIdx.x;
    const int base = blockIdx.x * 1024;
    int v[4];
    int s = 0;
    #pragma unroll
    for (int i = 0; i < 4; ++i) {
        int idx = base + t * 4 + i;
        v[i] = (idx < n) ? deg[idx] : 0;
        s += v[i];
    }
    sd[t] = s;
    __syncthreads();
    const int mine = s;
    for (int o = 1; o < 256; o <<= 1) {
        int add = (t >= o) ? sd[t - o] : 0;
        __syncthreads();
        sd[t] += add;
        __syncthreads();
    }
    int excl = sd[t] - mine + bsum[blockIdx.x];
    #pragma unroll
    for (int i = 0; i < 4; ++i) {
        int idx = base + t * 4 + i;
        if (idx < n) { offs[idx] = excl; excl += v[i]; }
    }
}

__global__ void fill_csr(const int* __restrict__ src, const int* __restrict__ dst,
                         const int* __restrict__ offs, int* __restrict__ cnt,
                         int* __restrict__ csr, int e) {
    int i = blockIdx.x * 256 + threadIdx.x;
    if (i < e) {
        int d = dst[i];
        int p = offs[d] + atomicAdd(&cnt[d], 1);
        csr[p] = src[i];
    }
}

// ---------------------------------------------------------------------------
// Pack weights into MFMA-fragment-ordered split-bf16 planes.
// Each packed buffer covers KTOT=256 k: [hi: 8 steps x 8ct x 64l x 8] [lo: same].
// Layer buffers concatenate W_self (steps 0-3) and W_neigh (steps 4-7).
// Lane l of fragment (step, ct) holds col = ct*16 + (l&15), k = step*32 + (l>>4)*8 + j.
// ---------------------------------------------------------------------------
__global__ void pack_weights(const float* __restrict__ W_t, const float* __restrict__ Ws0,
                             const float* __restrict__ Wn0, const float* __restrict__ Ws1,
                             const float* __restrict__ Wn1,
                             unsigned short* p_t, unsigned short* p_l0, unsigned short* p_l1) {
    const int bid = blockIdx.x;
    const float* W; unsigned short* out; int b0; int S0;
    if (bid < 16)      { W = W_t; out = p_t;  b0 = 0;  S0 = 0; }
    else if (bid < 24) { W = Ws0; out = p_l0; b0 = 16; S0 = 0; }
    else if (bid < 32) { W = Wn0; out = p_l0; b0 = 24; S0 = 4; }
    else if (bid < 40) { W = Ws1; out = p_l1; b0 = 32; S0 = 0; }
    else               { W = Wn1; out = p_l1; b0 = 40; S0 = 4; }
    const int idx = (bid - b0) * 256 + threadIdx.x;   // < K*16  (K = 256 or 128)
    const int step = idx >> 9;                         // local step within this matrix
    const int r = idx & 511;                           // ct*64 + lane
    const int l = r & 63;
    const int col = (r >> 6) * 16 + (l & 15);
    const int k0 = step * 32 + ((l >> 4) << 3);        // local k within this matrix
    const size_t o = (size_t)(S0 + step) * 4096 + (size_t)r * 8;
    #pragma unroll
    for (int j = 0; j < 8; ++j) {
        float f = W[(k0 + j) * HIDDEN + col];
        unsigned short h = f2bf(f);
        out[o + j] = h;
        out[32768 + o + j] = f2bf(f - bf2f(h));
    }
}

// ---------------------------------------------------------------------------
// Pipelined MFMA GEMM, f32 emulated via split bf16 (hh + lh + hl products).
// Logical A = [A0 | A1] (K=256 concat), W packed as above. out = act(A@W + bias).
// Block: 128 rows x 128 cols, 4 waves (2x2), wave tile 64x64, K-step 32, 8 steps.
// 2-phase pipeline: issue loads(t+1) -> compute(t) -> ds_write A(t+1) -> barrier.
// ---------------------------------------------------------------------------
template <int K0, bool RELU>
__launch_bounds__(256, 2)
__global__ void gemm_mfma(const float* __restrict__ A0, const float* __restrict__ A1,
                          const unsigned short* __restrict__ Wp,
                          const float* __restrict__ bias,
                          float* __restrict__ out, int nrows) {
    __shared__ __align__(16) unsigned short Ah[2][8][64][8];
    __shared__ __align__(16) unsigned short Al[2][8][64][8];
    __shared__ __align__(16) unsigned short Bh[2][8][64][8];
    __shared__ __align__(16) unsigned short Bl[2][8][64][8];

    const int t = threadIdx.x;
    const int lane = t & 63;
    const int w = t >> 6;
    const int wr = w >> 1, wc = w & 1;
    const int blockRow0 = blockIdx.x * 128;

    // staging coordinates for this thread (2 cells: flat = t, t+256)
    int srow[2], skk[2], srt[2], scl[2];
    #pragma unroll
    for (int u = 0; u < 2; ++u) {
        const int flat = t + u * 256;
        srt[u] = flat >> 6;
        scl[u] = flat & 63;
        int row = blockRow0 + srt[u] * 16 + (scl[u] & 15);
        srow[u] = min(row, nrows - 1);
        skk[u] = (scl[u] >> 4) << 3;
    }

    f32x4 acc[4][4];
    #pragma unroll
    for (int i = 0; i < 4; ++i)
        #pragma unroll
        for (int j = 0; j < 4; ++j) acc[i][j] = (f32x4){0.f, 0.f, 0.f, 0.f};

    auto loadA = [&](int step, float4 (&fa)[2][2]) {
        const int kt = step * 32;
        #pragma unroll
        for (int u = 0; u < 2; ++u) {
            const int kk = kt + skk[u];
            const float* p = (kk < K0) ? (A0 + (size_t)srow[u] * K0 + kk)
                                       : (A1 + (size_t)srow[u] * (256 - K0) + (kk - K0));
            fa[u][0] = *(const float4*)p;
            fa[u][1] = *(const float4*)(p + 4);
        }
    };
    auto stageW = [&](int buf, int step) {
        const unsigned short* WpH = Wp + (size_t)step * 4096 + (w * 2) * 512 + lane * 8;
        gload16(WpH,       &Bh[buf][w * 2][0][0]);
        gload16(WpH + 512, &Bh[buf][w * 2 + 1][0][0]);
        gload16(WpH + 32768,       &Bl[buf][w * 2][0][0]);
        gload16(WpH + 32768 + 512, &Bl[buf][w * 2 + 1][0][0]);
    };
    auto writeA = [&](int buf, float4 (&fa)[2][2]) {
        #pragma unroll
        for (int u = 0; u < 2; ++u) {
            float fv[8] = {fa[u][0].x, fa[u][0].y, fa[u][0].z, fa[u][0].w,
                           fa[u][1].x, fa[u][1].y, fa[u][1].z, fa[u][1].w};
            union { short8 v; unsigned short u16[8]; } vh, vl;
            #pragma unroll
            for (int j = 0; j < 8; ++j) {
                unsigned short h = f2bf(fv[j]);
                vh.u16[j] = h;
                vl.u16[j] = f2bf(fv[j] - bf2f(h));
            }
            *(short8*)&Ah[buf][srt[u]][scl[u]][0] = vh.v;
            *(short8*)&Al[buf][srt[u]][scl[u]][0] = vl.v;
        }
    };
    auto compute = [&](int buf) {
        short8 bh[4], bl[4];
        #pragma unroll
        for (int c4 = 0; c4 < 4; ++c4) {
            bh[c4] = *(const short8*)&Bh[buf][wc * 4 + c4][lane][0];
            bl[c4] = *(const short8*)&Bl[buf][wc * 4 + c4][lane][0];
        }
        #pragma unroll
        for (int r4 = 0; r4 < 4; ++r4) {
            short8 ah = *(const short8*)&Ah[buf][wr * 4 + r4][lane][0];
            short8 al = *(const short8*)&Al[buf][wr * 4 + r4][lane][0];
            #pragma unroll
            for (int c4 = 0; c4 < 4; ++c4) {
                acc[r4][c4] = __builtin_amdgcn_mfma_f32_16x16x32_bf16(ah, bh[c4], acc[r4][c4], 0, 0, 0);
                acc[r4][c4] = __builtin_amdgcn_mfma_f32_16x16x32_bf16(al, bh[c4], acc[r4][c4], 0, 0, 0);
                acc[r4][c4] = __builtin_amdgcn_mfma_f32_16x16x32_bf16(ah, bl[c4], acc[r4][c4], 0, 0, 0);
            }
        }
    };

    // prologue: stage step 0
    {
        float4 fa[2][2];
        loadA(0, fa);
        stageW(0, 0);
        writeA(0, fa);
    }
    __syncthreads();

    #pragma unroll
    for (int step = 0; step < 8; ++step) {
        const int cur = step & 1;
        float4 fn[2][2];
        if (step < 7) {
            loadA(step + 1, fn);          // A loads to regs, in flight during compute
            stageW(cur ^ 1, step + 1);    // W DMA to other buffer, drains at barrier
        }
        compute(cur);
        if (step < 7) writeA(cur ^ 1, fn); // waits A regs (had compute-time to land)
        __syncthreads();
    }

    // epilogue: bias (+relu), coalesced f32 stores
    #pragma unroll
    for (int c4 = 0; c4 < 4; ++c4) {
        const int col = (wc * 4 + c4) * 16 + (lane & 15);
        const float bc = bias[col];
        #pragma unroll
        for (int r4 = 0; r4 < 4; ++r4) {
            const int r0 = blockRow0 + (wr * 4 + r4) * 16 + ((lane >> 4) << 2);
            #pragma unroll
            for (int j = 0; j < 4; ++j) {
                const int r = r0 + j;
                if (r < nrows) {
                    float v = acc[r4][c4][j] + bc;
                    if (RELU) v = fmaxf(v, 0.f);
                    out[(size_t)r * HIDDEN + col] = v;
                }
            }
        }
    }
}

// ---------------------------------------------------------------------------
// Neighbor mean (f32 rows): one wave per node, lane owns 2 cols, 8-deep unroll.
// ---------------------------------------------------------------------------
__global__ void aggregate(const float* __restrict__ h, const int* __restrict__ offs,
                          const int* __restrict__ deg, const int* __restrict__ csr,
                          float* __restrict__ agg, int n) {
    const int node = blockIdx.x * 4 + (threadIdx.x >> 6);
    if (node >= n) return;
    const int lane = threadIdx.x & 63;
    const int start = offs[node];
    const int d = deg[node];
    float ax = 0.f, ay = 0.f;
    int i = 0;
    for (; i + 7 < d; i += 8) {
        int s[8];
        #pragma unroll
        for (int j = 0; j < 8; ++j) s[j] = csr[start + i + j];
        float2 v[8];
        #pragma unroll
        for (int j = 0; j < 8; ++j) v[j] = *(const float2*)&h[(size_t)s[j] * HIDDEN + lane * 2];
        #pragma unroll
        for (int j = 0; j < 8; ++j) { ax += v[j].x; ay += v[j].y; }
    }
    for (; i < d; ++i) {
        int s0 = csr[start + i];
        float2 v0 = *(const float2*)&h[(size_t)s0 * HIDDEN + lane * 2];
        ax += v0.x;
        ay += v0.y;
    }
    const float inv = 1.0f / (float)max(d, 1);
    float2 o;
    o.x = ax * inv;
    o.y = ay * inv;
    *(float2*)&agg[(size_t)node * HIDDEN + lane * 2] = o;
}

// ---------------------------------------------------------------------------
// Final projection: out[r] = dot(h[r], W_fin). One wave per row.
// ---------------------------------------------------------------------------
__global__ void final_dot(const float* __restrict__ h, const float* __restrict__ wfin,
                          float* __restrict__ out, int n) {
    const int node = blockIdx.x * 4 + (threadIdx.x >> 6);
    if (node >= n) return;
    const int lane = threadIdx.x & 63;
    float2 v = *(const float2*)&h[(size_t)node * HIDDEN + lane * 2];
    float2 wv = *(const float2*)&wfin[lane * 2];
    float s = v.x * wv.x + v.y * wv.y;
    #pragma unroll
    for (int o = 32; o > 0; o >>= 1) s += __shfl_down(s, o, 64);
    if (lane == 0) out[node] = s;
}

// ---------------------------------------------------------------------------
extern "C" void kernel_launch(void* const* d_in, const int* in_sizes, int n_in,
                              void* d_out, int out_size, void* d_ws, size_t ws_size,
                              hipStream_t stream) {
    const float* x     = (const float*)d_in[0];
    const float* W_t   = (const float*)d_in[1];
    const float* b_t   = (const float*)d_in[2];
    const float* W_s0  = (const float*)d_in[3];
    const float* b_s0  = (const float*)d_in[4];
    const float* W_n0  = (const float*)d_in[5];
    const float* W_s1  = (const float*)d_in[6];
    const float* b_s1  = (const float*)d_in[7];
    const float* W_n1  = (const float*)d_in[8];
    const float* W_fin = (const float*)d_in[9];
    const int*   src   = (const int*)d_in[10];
    const int*   dst   = (const int*)d_in[11];
    float* out = (float*)d_out;

    const int N = in_sizes[0] / 256;   // 100000
    const int E = in_sizes[10];        // 1600000

    // workspace carving (256B aligned)
    size_t off_b = 0;
    auto carve = [&](size_t bytes) {
        size_t cur = off_b;
        off_b = (off_b + bytes + 255) & ~(size_t)255;
        return cur;
    };
    char* base = (char*)d_ws;
    int* deg  = (int*)(base + carve((size_t)(2 * N) * 4));  // deg + cnt adjacent
    int* cnt  = deg + N;
    int* offs = (int*)(base + carve((size_t)N * 4));
    int* bsum = (int*)(base + carve(1024 * 4));
    int* csr  = (int*)(base + carve((size_t)E * 4));
    unsigned short* wp_t  = (unsigned short*)(base + carve((size_t)65536 * 2));
    unsigned short* wp_l0 = (unsigned short*)(base + carve((size_t)65536 * 2));
    unsigned short* wp_l1 = (unsigned short*)(base + carve((size_t)65536 * 2));
    float* hA  = (float*)(base + carve((size_t)N * HIDDEN * 4));
    float* hB  = (float*)(base + carve((size_t)N * HIDDEN * 4));
    float* agp = (float*)(base + carve((size_t)N * HIDDEN * 4));
    (void)ws_size; (void)n_in; (void)out_size;

    const int nbScan = (N + 1023) / 1024;   // 98 (<=256 required by scan_bsum)

    // --- CSR build ---
    hipLaunchKernelGGL(zero_ints, dim3((2 * N + 255) / 256), dim3(256), 0, stream, deg, 2 * N);
    hipLaunchKernelGGL(count_deg, dim3((E + 255) / 256), dim3(256), 0, stream, dst, deg, E);
    hipLaunchKernelGGL(scan_partial, dim3(nbScan), dim3(256), 0, stream, deg, bsum, N);
    hipLaunchKernelGGL(scan_bsum, dim3(1), dim3(256), 0, stream, bsum, nbScan);
    hipLaunchKernelGGL(scan_offsets, dim3(nbScan), dim3(256), 0, stream, deg, bsum, offs, N);
    hipLaunchKernelGGL(fill_csr, dim3((E + 255) / 256), dim3(256), 0, stream, src, dst, offs, cnt, csr, E);

    // --- weight packing (48 tiny blocks) ---
    hipLaunchKernelGGL(pack_weights, dim3(48), dim3(256), 0, stream,
                       W_t, W_s0, W_n0, W_s1, W_n1, wp_t, wp_l0, wp_l1);

    const int gemmGrid = (N + 127) / 128;
    const int nodeGrid = (N + 3) / 4;

    // h0 = x @ W_t + b_t
    hipLaunchKernelGGL((gemm_mfma<256, false>), dim3(gemmGrid), dim3(256), 0, stream,
                       x, (const float*)nullptr, wp_t, b_t, hA, N);
    // layer 0
    hipLaunchKernelGGL(aggregate, dim3(nodeGrid), dim3(256), 0, stream, hA, offs, deg, csr, agp, N);
    hipLaunchKernelGGL((gemm_mfma<128, true>), dim3(gemmGrid), dim3(256), 0, stream,
                       hA, agp, wp_l0, b_s0, hB, N);
    // layer 1
    hipLaunchKernelGGL(aggregate, dim3(nodeGrid), dim3(256), 0, stream, hB, offs, deg, csr, agp, N);
    hipLaunchKernelGGL((gemm_mfma<128, true>), dim3(gemmGrid), dim3(256), 0, stream,
                       hB, agp, wp_l1, b_s1, hA, N);
    // final projection
    hipLaunchKernelGGL(final_dot, dim3(nodeGrid), dim3(256), 0, stream, hA, W_fin, out, N);
}

// Round 4
// 430.069 us; speedup vs baseline: 1.7502x; 1.3209x over previous
//
#include <hip/hip_runtime.h>
#include <hip/hip_fp16.h>

#define HIDDEN 128

using short8 = __attribute__((ext_vector_type(8))) short;
using f32x4  = __attribute__((ext_vector_type(4))) float;

// ---------------------------------------------------------------------------
// bf16 split helpers (RNE)
// ---------------------------------------------------------------------------
__device__ __forceinline__ unsigned short f2bf(float f) {
    unsigned u = __float_as_uint(f);
    return (unsigned short)((u + 0x7fffu + ((u >> 16) & 1u)) >> 16);
}
__device__ __forceinline__ float bf2f(unsigned short h) {
    return __uint_as_float(((unsigned)h) << 16);
}

__device__ __forceinline__ void gload16(const void* g, void* l) {
    __builtin_amdgcn_global_load_lds((const __attribute__((address_space(1))) void*)g,
                                     (__attribute__((address_space(3))) void*)l,
                                     16, 0, 0);
}

// ---------------------------------------------------------------------------
// CSR build kernels
// ---------------------------------------------------------------------------
__global__ void zero_ints(int* __restrict__ a, int n) {
    int i = blockIdx.x * 256 + threadIdx.x;
    if (i < n) a[i] = 0;
}

__global__ void count_deg(const int* __restrict__ dst, int* __restrict__ deg, int e) {
    int i = blockIdx.x * 256 + threadIdx.x;
    if (i < e) atomicAdd(&deg[dst[i]], 1);
}

__global__ void scan_partial(const int* __restrict__ deg, int* __restrict__ bsum, int n) {
    __shared__ int sd[256];
    const int t = threadIdx.x;
    const int base = blockIdx.x * 1024;
    int s = 0;
    #pragma unroll
    for (int i = 0; i < 4; ++i) {
        int idx = base + t * 4 + i;
        if (idx < n) s += deg[idx];
    }
    sd[t] = s;
    __syncthreads();
    for (int o = 128; o > 0; o >>= 1) {
        if (t < o) sd[t] += sd[t + o];
        __syncthreads();
    }
    if (t == 0) bsum[blockIdx.x] = sd[0];
}

__global__ void scan_bsum(int* __restrict__ bsum, int nb) {
    __shared__ int sd[256];
    const int t = threadIdx.x;
    int v = (t < nb) ? bsum[t] : 0;
    sd[t] = v;
    __syncthreads();
    for (int o = 1; o < 256; o <<= 1) {
        int add = (t >= o) ? sd[t - o] : 0;
        __syncthreads();
        sd[t] += add;
        __syncthreads();
    }
    if (t < nb) bsum[t] = sd[t] - v;
}

__global__ void scan_offsets(const int* __restrict__ deg, const int* __restrict__ bsum,
                             int* __restrict__ offs, int n) {
    __shared__ int sd[256];
    const int t = threadIdx.x;
    const int base = blockIdx.x * 1024;
    int v[4];
    int s = 0;
    #pragma unroll
    for (int i = 0; i < 4; ++i) {
        int idx = base + t * 4 + i;
        v[i] = (idx < n) ? deg[idx] : 0;
        s += v[i];
    }
    sd[t] = s;
    __syncthreads();
    const int mine = s;
    for (int o = 1; o < 256; o <<= 1) {
        int add = (t >= o) ? sd[t - o] : 0;
        __syncthreads();
        sd[t] += add;
        __syncthreads();
    }
    int excl = sd[t] - mine + bsum[blockIdx.x];
    #pragma unroll
    for (int i = 0; i < 4; ++i) {
        int idx = base + t * 4 + i;
        if (idx < n) { offs[idx] = excl; excl += v[i]; }
    }
}

__global__ void fill_csr(const int* __restrict__ src, const int* __restrict__ dst,
                         const int* __restrict__ offs, int* __restrict__ cnt,
                         int* __restrict__ csr, int e) {
    int i = blockIdx.x * 256 + threadIdx.x;
    if (i < e) {
        int d = dst[i];
        int p = offs[d] + atomicAdd(&cnt[d], 1);
        csr[p] = src[i];
    }
}

// ---------------------------------------------------------------------------
// Pack weights into MFMA-fragment-ordered split-bf16 planes.
// Buffer covers K=256: [hi: 8 steps x 8ct x 64lane x 8] then [lo: same at +32768].
// Layer buffers: W_self at steps 0-3, W_neigh at steps 4-7.
// Lane l of fragment (step, ct) holds col = ct*16 + (l&15), k = step*32 + (l>>4)*8 + j.
// ---------------------------------------------------------------------------
__global__ void pack_weights(const float* __restrict__ W_t, const float* __restrict__ Ws0,
                             const float* __restrict__ Wn0, const float* __restrict__ Ws1,
                             const float* __restrict__ Wn1,
                             unsigned short* p_t, unsigned short* p_l0, unsigned short* p_l1) {
    const int bid = blockIdx.x;
    const float* W; unsigned short* out; int b0; int S0;
    if (bid < 16)      { W = W_t; out = p_t;  b0 = 0;  S0 = 0; }
    else if (bid < 24) { W = Ws0; out = p_l0; b0 = 16; S0 = 0; }
    else if (bid < 32) { W = Wn0; out = p_l0; b0 = 24; S0 = 4; }
    else if (bid < 40) { W = Ws1; out = p_l1; b0 = 32; S0 = 0; }
    else               { W = Wn1; out = p_l1; b0 = 40; S0 = 4; }
    const int idx = (bid - b0) * 256 + threadIdx.x;   // < K*16  (K = 256 or 128)
    const int step = idx >> 9;                         // local step within this matrix
    const int r = idx & 511;                           // ct*64 + lane
    const int l = r & 63;
    const int col = (r >> 6) * 16 + (l & 15);
    const int k0 = step * 32 + ((l >> 4) << 3);        // local k within this matrix
    const size_t o = (size_t)(S0 + step) * 4096 + (size_t)r * 8;
    #pragma unroll
    for (int j = 0; j < 8; ++j) {
        float f = W[(k0 + j) * HIDDEN + col];
        unsigned short h = f2bf(f);
        out[o + j] = h;
        out[32768 + o + j] = f2bf(f - bf2f(h));
    }
}

// ---------------------------------------------------------------------------
// Pipelined MFMA GEMM, f32 emulated via split bf16 (hh + lh + hl products).
// A is fp16 (layers, K=128 self + 128 neigh) or f32 (transform, K=256).
// Block 128x128, 4 waves (2x2), wave tile 64x64, K-step 32, 8 steps,
// 2-phase pipeline: issue loads(t+1) -> compute(t) -> ds_write A(t+1) -> barrier.
// FINAL: fuse out = relu(..) @ wfin (per-row dot) instead of storing h.
// ---------------------------------------------------------------------------
template <bool F32A, bool RELU, bool FINAL>
__launch_bounds__(256, 2)
__global__ void gemm_mfma(const void* __restrict__ A0v, const void* __restrict__ A1v,
                          const unsigned short* __restrict__ Wp,
                          const float* __restrict__ bias,
                          const float* __restrict__ wfin,
                          void* __restrict__ outv, int nrows) {
    __shared__ __align__(16) unsigned short Ah[2][8][64][8];
    __shared__ __align__(16) unsigned short Al[2][8][64][8];
    __shared__ __align__(16) unsigned short Bh[2][8][64][8];
    __shared__ __align__(16) unsigned short Bl[2][8][64][8];
    __shared__ float red[FINAL ? 128 : 1][2];

    const int t = threadIdx.x;
    const int lane = t & 63;
    const int w = t >> 6;
    const int wr = w >> 1, wc = w & 1;
    const int blockRow0 = blockIdx.x * 128;

    // staging coordinates for this thread (2 cells: flat = t, t+256)
    int srow[2], skk[2], srt[2], scl[2];
    #pragma unroll
    for (int u = 0; u < 2; ++u) {
        const int flat = t + u * 256;
        srt[u] = flat >> 6;
        scl[u] = flat & 63;
        int row = blockRow0 + srt[u] * 16 + (scl[u] & 15);
        srow[u] = min(row, nrows - 1);
        skk[u] = (scl[u] >> 4) << 3;
    }

    f32x4 acc[4][4];
    #pragma unroll
    for (int i = 0; i < 4; ++i)
        #pragma unroll
        for (int j = 0; j < 4; ++j) acc[i][j] = (f32x4){0.f, 0.f, 0.f, 0.f};

    auto loadA = [&](int step, float (&fv)[2][8]) {
        const int kt = step * 32;
        #pragma unroll
        for (int u = 0; u < 2; ++u) {
            const int kk = kt + skk[u];
            if constexpr (F32A) {
                const float* p = (const float*)A0v + (size_t)srow[u] * 256 + kk;
                float4 f0 = *(const float4*)p;
                float4 f1 = *(const float4*)(p + 4);
                fv[u][0] = f0.x; fv[u][1] = f0.y; fv[u][2] = f0.z; fv[u][3] = f0.w;
                fv[u][4] = f1.x; fv[u][5] = f1.y; fv[u][6] = f1.z; fv[u][7] = f1.w;
            } else {
                const __half* p = (kk < 128)
                    ? (const __half*)A0v + (size_t)srow[u] * HIDDEN + kk
                    : (const __half*)A1v + (size_t)srow[u] * HIDDEN + (kk - 128);
                uint4 raw = *(const uint4*)p;
                __half2* hp = (__half2*)&raw;
                #pragma unroll
                for (int m = 0; m < 4; ++m) {
                    float2 f = __half22float2(hp[m]);
                    fv[u][2 * m]     = f.x;
                    fv[u][2 * m + 1] = f.y;
                }
            }
        }
    };
    auto stageW = [&](int buf, int step) {
        const unsigned short* WpH = Wp + (size_t)step * 4096 + (w * 2) * 512 + lane * 8;
        gload16(WpH,       &Bh[buf][w * 2][0][0]);
        gload16(WpH + 512, &Bh[buf][w * 2 + 1][0][0]);
        gload16(WpH + 32768,       &Bl[buf][w * 2][0][0]);
        gload16(WpH + 32768 + 512, &Bl[buf][w * 2 + 1][0][0]);
    };
    auto writeA = [&](int buf, float (&fv)[2][8]) {
        #pragma unroll
        for (int u = 0; u < 2; ++u) {
            union { short8 v; unsigned short u16[8]; } vh, vl;
            #pragma unroll
            for (int j = 0; j < 8; ++j) {
                unsigned short h = f2bf(fv[u][j]);
                vh.u16[j] = h;
                vl.u16[j] = f2bf(fv[u][j] - bf2f(h));
            }
            *(short8*)&Ah[buf][srt[u]][scl[u]][0] = vh.v;
            *(short8*)&Al[buf][srt[u]][scl[u]][0] = vl.v;
        }
    };
    auto compute = [&](int buf) {
        short8 bh[4], bl[4];
        #pragma unroll
        for (int c4 = 0; c4 < 4; ++c4) {
            bh[c4] = *(const short8*)&Bh[buf][wc * 4 + c4][lane][0];
            bl[c4] = *(const short8*)&Bl[buf][wc * 4 + c4][lane][0];
        }
        #pragma unroll
        for (int r4 = 0; r4 < 4; ++r4) {
            short8 ah = *(const short8*)&Ah[buf][wr * 4 + r4][lane][0];
            short8 al = *(const short8*)&Al[buf][wr * 4 + r4][lane][0];
            #pragma unroll
            for (int c4 = 0; c4 < 4; ++c4) {
                acc[r4][c4] = __builtin_amdgcn_mfma_f32_16x16x32_bf16(ah, bh[c4], acc[r4][c4], 0, 0, 0);
                acc[r4][c4] = __builtin_amdgcn_mfma_f32_16x16x32_bf16(al, bh[c4], acc[r4][c4], 0, 0, 0);
                acc[r4][c4] = __builtin_amdgcn_mfma_f32_16x16x32_bf16(ah, bl[c4], acc[r4][c4], 0, 0, 0);
            }
        }
    };

    // prologue: stage step 0
    {
        float fa[2][8];
        loadA(0, fa);
        stageW(0, 0);
        writeA(0, fa);
    }
    __syncthreads();

    #pragma unroll
    for (int step = 0; step < 8; ++step) {
        const int cur = step & 1;
        float fn[2][8];
        if (step < 7) {
            loadA(step + 1, fn);          // A loads to regs, in flight during compute
            stageW(cur ^ 1, step + 1);    // W DMA to other buffer, drains at barrier
        }
        compute(cur);
        if (step < 7) writeA(cur ^ 1, fn); // A regs had the compute phase to land
        __syncthreads();
    }

    // epilogue
    if constexpr (FINAL) {
        // fused out = relu(acc + bias) @ wfin
        float wf[4], bc[4];
        #pragma unroll
        for (int c4 = 0; c4 < 4; ++c4) {
            const int col = (wc * 4 + c4) * 16 + (lane & 15);
            wf[c4] = wfin[col];
            bc[c4] = bias[col];
        }
        float part[4][4];
        #pragma unroll
        for (int r4 = 0; r4 < 4; ++r4)
            #pragma unroll
            for (int j = 0; j < 4; ++j) {
                float s = 0.f;
                #pragma unroll
                for (int c4 = 0; c4 < 4; ++c4) {
                    float v = acc[r4][c4][j] + bc[c4];
                    if (RELU) v = fmaxf(v, 0.f);
                    s = fmaf(v, wf[c4], s);
                }
                part[r4][j] = s;
            }
        #pragma unroll
        for (int o = 1; o < 16; o <<= 1)
            #pragma unroll
            for (int r4 = 0; r4 < 4; ++r4)
                #pragma unroll
                for (int j = 0; j < 4; ++j)
                    part[r4][j] += __shfl_xor(part[r4][j], o, 64);
        if ((lane & 15) == 0) {
            #pragma unroll
            for (int r4 = 0; r4 < 4; ++r4)
                #pragma unroll
                for (int j = 0; j < 4; ++j) {
                    const int rl = wr * 64 + r4 * 16 + ((lane >> 4) << 2) + j;
                    red[rl][wc] = part[r4][j];
                }
        }
        __syncthreads();
        if (t < 128) {
            const int r = blockRow0 + t;
            if (r < nrows) ((float*)outv)[r] = red[t][0] + red[t][1];
        }
    } else {
        __half* out = (__half*)outv;
        #pragma unroll
        for (int c4 = 0; c4 < 4; ++c4) {
            const int col = (wc * 4 + c4) * 16 + (lane & 15);
            const float bc = bias[col];
            #pragma unroll
            for (int r4 = 0; r4 < 4; ++r4) {
                const int r0 = blockRow0 + (wr * 4 + r4) * 16 + ((lane >> 4) << 2);
                #pragma unroll
                for (int j = 0; j < 4; ++j) {
                    const int r = r0 + j;
                    if (r < nrows) {
                        float v = acc[r4][c4][j] + bc;
                        if (RELU) v = fmaxf(v, 0.f);
                        out[(size_t)r * HIDDEN + col] = __float2half(v);
                    }
                }
            }
        }
    }
}

// ---------------------------------------------------------------------------
// Neighbor mean over fp16 h. One wave per node; 2 edges per wave-load
// (32 lanes x 8B cover one 256B row), 4-deep per half -> 8 rows in flight.
// ---------------------------------------------------------------------------
__global__ void aggregate_h16(const __half* __restrict__ h, const int* __restrict__ offs,
                              const int* __restrict__ deg, const int* __restrict__ csr,
                              __half* __restrict__ agg, int n) {
    const int node = blockIdx.x * 4 + (threadIdx.x >> 6);
    if (node >= n) return;
    const int lane = threadIdx.x & 63;
    const int eh = lane >> 5;           // edge slot (0/1)
    const int c4 = (lane & 31) * 4;     // 4 cols per lane
    const int start = offs[node];
    const int d = deg[node];
    float a0 = 0.f, a1 = 0.f, a2 = 0.f, a3 = 0.f;
    int i = eh;
    for (; i + 6 < d; i += 8) {
        int s[4];
        #pragma unroll
        for (int j = 0; j < 4; ++j) s[j] = csr[start + i + 2 * j];
        #pragma unroll
        for (int j = 0; j < 4; ++j) {
            uint2 raw = *(const uint2*)&h[(size_t)s[j] * HIDDEN + c4];
            float2 f0 = __half22float2(*(__half2*)&raw.x);
            float2 f1 = __half22float2(*(__half2*)&raw.y);
            a0 += f0.x; a1 += f0.y; a2 += f1.x; a3 += f1.y;
        }
    }
    for (; i < d; i += 2) {
        int s0 = csr[start + i];
        uint2 raw = *(const uint2*)&h[(size_t)s0 * HIDDEN + c4];
        float2 f0 = __half22float2(*(__half2*)&raw.x);
        float2 f1 = __half22float2(*(__half2*)&raw.y);
        a0 += f0.x; a1 += f0.y; a2 += f1.x; a3 += f1.y;
    }
    // combine the two edge-slot halves (lane ^ 32)
    a0 += __shfl_xor(a0, 32, 64);
    a1 += __shfl_xor(a1, 32, 64);
    a2 += __shfl_xor(a2, 32, 64);
    a3 += __shfl_xor(a3, 32, 64);
    if (eh == 0) {
        const float inv = 1.0f / (float)max(d, 1);
        __half2 o0 = __floats2half2_rn(a0 * inv, a1 * inv);
        __half2 o1 = __floats2half2_rn(a2 * inv, a3 * inv);
        uint2 raw;
        raw.x = *(unsigned*)&o0;
        raw.y = *(unsigned*)&o1;
        *(uint2*)&agg[(size_t)node * HIDDEN + c4] = raw;
    }
}

// ---------------------------------------------------------------------------
extern "C" void kernel_launch(void* const* d_in, const int* in_sizes, int n_in,
                              void* d_out, int out_size, void* d_ws, size_t ws_size,
                              hipStream_t stream) {
    const float* x     = (const float*)d_in[0];
    const float* W_t   = (const float*)d_in[1];
    const float* b_t   = (const float*)d_in[2];
    const float* W_s0  = (const float*)d_in[3];
    const float* b_s0  = (const float*)d_in[4];
    const float* W_n0  = (const float*)d_in[5];
    const float* W_s1  = (const float*)d_in[6];
    const float* b_s1  = (const float*)d_in[7];
    const float* W_n1  = (const float*)d_in[8];
    const float* W_fin = (const float*)d_in[9];
    const int*   src   = (const int*)d_in[10];
    const int*   dst   = (const int*)d_in[11];
    float* out = (float*)d_out;

    const int N = in_sizes[0] / 256;   // 100000
    const int E = in_sizes[10];        // 1600000

    // workspace carving (256B aligned)
    size_t off_b = 0;
    auto carve = [&](size_t bytes) {
        size_t cur = off_b;
        off_b = (off_b + bytes + 255) & ~(size_t)255;
        return cur;
    };
    char* base = (char*)d_ws;
    int* deg  = (int*)(base + carve((size_t)(2 * N) * 4));  // deg + cnt adjacent
    int* cnt  = deg + N;
    int* offs = (int*)(base + carve((size_t)N * 4));
    int* bsum = (int*)(base + carve(1024 * 4));
    int* csr  = (int*)(base + carve((size_t)E * 4));
    unsigned short* wp_t  = (unsigned short*)(base + carve((size_t)65536 * 2));
    unsigned short* wp_l0 = (unsigned short*)(base + carve((size_t)65536 * 2));
    unsigned short* wp_l1 = (unsigned short*)(base + carve((size_t)65536 * 2));
    __half* hA  = (__half*)(base + carve((size_t)N * HIDDEN * 2));
    __half* hB  = (__half*)(base + carve((size_t)N * HIDDEN * 2));
    __half* agp = (__half*)(base + carve((size_t)N * HIDDEN * 2));
    (void)ws_size; (void)n_in; (void)out_size;

    const int nbScan = (N + 1023) / 1024;   // 98 (<=256 required by scan_bsum)

    // --- CSR build ---
    hipLaunchKernelGGL(zero_ints, dim3((2 * N + 255) / 256), dim3(256), 0, stream, deg, 2 * N);
    hipLaunchKernelGGL(count_deg, dim3((E + 255) / 256), dim3(256), 0, stream, dst, deg, E);
    hipLaunchKernelGGL(scan_partial, dim3(nbScan), dim3(256), 0, stream, deg, bsum, N);
    hipLaunchKernelGGL(scan_bsum, dim3(1), dim3(256), 0, stream, bsum, nbScan);
    hipLaunchKernelGGL(scan_offsets, dim3(nbScan), dim3(256), 0, stream, deg, bsum, offs, N);
    hipLaunchKernelGGL(fill_csr, dim3((E + 255) / 256), dim3(256), 0, stream, src, dst, offs, cnt, csr, E);

    // --- weight packing (48 tiny blocks) ---
    hipLaunchKernelGGL(pack_weights, dim3(48), dim3(256), 0, stream,
                       W_t, W_s0, W_n0, W_s1, W_n1, wp_t, wp_l0, wp_l1);

    const int gemmGrid = (N + 127) / 128;
    const int nodeGrid = (N + 3) / 4;

    // h0 = x @ W_t + b_t  (f32 A path)
    hipLaunchKernelGGL((gemm_mfma<true, false, false>), dim3(gemmGrid), dim3(256), 0, stream,
                       (const void*)x, (const void*)nullptr, wp_t, b_t, (const float*)nullptr,
                       (void*)hA, N);
    // layer 0
    hipLaunchKernelGGL(aggregate_h16, dim3(nodeGrid), dim3(256), 0, stream, hA, offs, deg, csr, agp, N);
    hipLaunchKernelGGL((gemm_mfma<false, true, false>), dim3(gemmGrid), dim3(256), 0, stream,
                       (const void*)hA, (const void*)agp, wp_l0, b_s0, (const float*)nullptr,
                       (void*)hB, N);
    // layer 1 + fused final projection
    hipLaunchKernelGGL(aggregate_h16, dim3(nodeGrid), dim3(256), 0, stream, hB, offs, deg, csr, agp, N);
    hipLaunchKernelGGL((gemm_mfma<false, true, true>), dim3(gemmGrid), dim3(256), 0, stream,
                       (const void*)hB, (const void*)agp, wp_l1, b_s1, W_fin,
                       (void*)out, N);
}

// Round 5
// 369.891 us; speedup vs baseline: 2.0350x; 1.1627x over previous
//
#include <hip/hip_runtime.h>
#include <hip/hip_fp16.h>

#define HIDDEN 128
#define BSHIFT 9                  // 512 nodes per bucket
#define NBUCK_MAX 256

using short8 = __attribute__((ext_vector_type(8))) short;
using f32x4  = __attribute__((ext_vector_type(4))) float;

// ---------------------------------------------------------------------------
// bf16 split helpers (RNE)
// ---------------------------------------------------------------------------
__device__ __forceinline__ unsigned short f2bf(float f) {
    unsigned u = __float_as_uint(f);
    return (unsigned short)((u + 0x7fffu + ((u >> 16) & 1u)) >> 16);
}
__device__ __forceinline__ float bf2f(unsigned short h) {
    return __uint_as_float(((unsigned)h) << 16);
}

__device__ __forceinline__ void gload16(const void* g, void* l) {
    __builtin_amdgcn_global_load_lds((const __attribute__((address_space(1))) void*)g,
                                     (__attribute__((address_space(3))) void*)l,
                                     16, 0, 0);
}

// ---------------------------------------------------------------------------
// CSR build kernels
// ---------------------------------------------------------------------------
__global__ void zero_ints(int* __restrict__ a, int n) {
    int i = blockIdx.x * 256 + threadIdx.x;
    if (i < n) a[i] = 0;
}

__global__ void count_deg(const int* __restrict__ dst, int* __restrict__ deg, int e) {
    int i = blockIdx.x * 256 + threadIdx.x;
    if (i < e) atomicAdd(&deg[dst[i]], 1);
}

__global__ void scan_partial(const int* __restrict__ deg, int* __restrict__ bsum, int n) {
    __shared__ int sd[256];
    const int t = threadIdx.x;
    const int base = blockIdx.x * 1024;
    int s = 0;
    #pragma unroll
    for (int i = 0; i < 4; ++i) {
        int idx = base + t * 4 + i;
        if (idx < n) s += deg[idx];
    }
    sd[t] = s;
    __syncthreads();
    for (int o = 128; o > 0; o >>= 1) {
        if (t < o) sd[t] += sd[t + o];
        __syncthreads();
    }
    if (t == 0) bsum[blockIdx.x] = sd[0];
}

__global__ void scan_bsum(int* __restrict__ bsum, int nb) {
    __shared__ int sd[256];
    const int t = threadIdx.x;
    int v = (t < nb) ? bsum[t] : 0;
    sd[t] = v;
    __syncthreads();
    for (int o = 1; o < 256; o <<= 1) {
        int add = (t >= o) ? sd[t - o] : 0;
        __syncthreads();
        sd[t] += add;
        __syncthreads();
    }
    if (t < nb) bsum[t] = sd[t] - v;
}

__global__ void scan_offsets(const int* __restrict__ deg, const int* __restrict__ bsum,
                             int* __restrict__ offs, int n) {
    __shared__ int sd[256];
    const int t = threadIdx.x;
    const int base = blockIdx.x * 1024;
    int v[4];
    int s = 0;
    #pragma unroll
    for (int i = 0; i < 4; ++i) {
        int idx = base + t * 4 + i;
        v[i] = (idx < n) ? deg[idx] : 0;
        s += v[i];
    }
    sd[t] = s;
    __syncthreads();
    const int mine = s;
    for (int o = 1; o < 256; o <<= 1) {
        int add = (t >= o) ? sd[t - o] : 0;
        __syncthreads();
        sd[t] += add;
        __syncthreads();
    }
    int excl = sd[t] - mine + bsum[blockIdx.x];
    #pragma unroll
    for (int i = 0; i < 4; ++i) {
        int idx = base + t * 4 + i;
        if (idx < n) { offs[idx] = excl; excl += v[i]; }
    }
}

__global__ void init_cursors(const int* __restrict__ offs, int* __restrict__ cursor, int nb) {
    const int b = threadIdx.x;
    if (b < nb) cursor[b] = offs[b << BSHIFT];
}

// P1: LDS-binned partition of edges into bucket-grouped (dst,src) pairs.
// Bucket regions in `pairs` use the same offsets as csr, so placement in P2
// stays within the region. Writes are ~168B contiguous runs (low amplification).
__launch_bounds__(256)
__global__ void partition_pairs(const int* __restrict__ src, const int* __restrict__ dst,
                                int* __restrict__ cursor,
                                unsigned long long* __restrict__ pairs, int e) {
    __shared__ int cnt[NBUCK_MAX];
    __shared__ int base[NBUCK_MAX];
    const int t = threadIdx.x;
    const int tile0 = blockIdx.x * 4096;
    cnt[t] = 0;
    __syncthreads();
    int s[16], d[16], b[16];
    #pragma unroll
    for (int j = 0; j < 16; ++j) {
        const int i = tile0 + j * 256 + t;
        if (i < e) {
            d[j] = dst[i];
            s[j] = src[i];
            b[j] = d[j] >> BSHIFT;
            atomicAdd(&cnt[b[j]], 1);
        } else {
            b[j] = -1;
        }
    }
    __syncthreads();
    const int c = cnt[t];
    base[t] = c ? atomicAdd(&cursor[t], c) : 0;
    __syncthreads();
    cnt[t] = 0;
    __syncthreads();
    #pragma unroll
    for (int j = 0; j < 16; ++j) {
        if (b[j] >= 0) {
            const int r = atomicAdd(&cnt[b[j]], 1);
            pairs[(size_t)base[b[j]] + r] =
                ((unsigned long long)(unsigned)d[j] << 32) | (unsigned)s[j];
        }
    }
}

// P2: one block per bucket; per-dst rank cursors in LDS; csr writes confined
// to the bucket's ~32KB region -> lines fully populated -> dense writeback.
__launch_bounds__(256)
__global__ void place_csr(const unsigned long long* __restrict__ pairs,
                          const int* __restrict__ offs,
                          int* __restrict__ csr, int n, int e) {
    __shared__ int cur[1 << BSHIFT];
    const int node0 = blockIdx.x << BSHIFT;
    const int nn = min(1 << BSHIFT, n - node0);
    const int t = threadIdx.x;
    for (int i = t; i < nn; i += 256) cur[i] = offs[node0 + i];
    __syncthreads();
    const int beg = offs[node0];
    const int end = (node0 + nn < n) ? offs[node0 + nn] : e;
    for (int i = beg + t; i < end; i += 256) {
        const unsigned long long pr = pairs[i];
        const int dd = (int)(pr >> 32);
        const int ss = (int)(unsigned)pr;
        const int p = atomicAdd(&cur[dd - node0], 1);
        csr[p] = ss;
    }
}

// ---------------------------------------------------------------------------
// Pack weights into MFMA-fragment-ordered split-bf16 planes.
// Buffer covers K=256: [hi: 8 steps x 8ct x 64lane x 8] then [lo: same at +32768].
// Layer buffers: W_self at steps 0-3, W_neigh at steps 4-7.
// Lane l of fragment (step, ct) holds col = ct*16 + (l&15), k = step*32 + (l>>4)*8 + j.
// ---------------------------------------------------------------------------
__global__ void pack_weights(const float* __restrict__ W_t, const float* __restrict__ Ws0,
                             const float* __restrict__ Wn0, const float* __restrict__ Ws1,
                             const float* __restrict__ Wn1,
                             unsigned short* p_t, unsigned short* p_l0, unsigned short* p_l1) {
    const int bid = blockIdx.x;
    const float* W; unsigned short* out; int b0; int S0;
    if (bid < 16)      { W = W_t; out = p_t;  b0 = 0;  S0 = 0; }
    else if (bid < 24) { W = Ws0; out = p_l0; b0 = 16; S0 = 0; }
    else if (bid < 32) { W = Wn0; out = p_l0; b0 = 24; S0 = 4; }
    else if (bid < 40) { W = Ws1; out = p_l1; b0 = 32; S0 = 0; }
    else               { W = Wn1; out = p_l1; b0 = 40; S0 = 4; }
    const int idx = (bid - b0) * 256 + threadIdx.x;   // < K*16  (K = 256 or 128)
    const int step = idx >> 9;                         // local step within this matrix
    const int r = idx & 511;                           // ct*64 + lane
    const int l = r & 63;
    const int col = (r >> 6) * 16 + (l & 15);
    const int k0 = step * 32 + ((l >> 4) << 3);        // local k within this matrix
    const size_t o = (size_t)(S0 + step) * 4096 + (size_t)r * 8;
    #pragma unroll
    for (int j = 0; j < 8; ++j) {
        float f = W[(k0 + j) * HIDDEN + col];
        unsigned short h = f2bf(f);
        out[o + j] = h;
        out[32768 + o + j] = f2bf(f - bf2f(h));
    }
}

// ---------------------------------------------------------------------------
// Pipelined MFMA GEMM, f32 emulated via split bf16 (hh + lh + hl products).
// A is fp16 (layers, K=128 self + 128 neigh) or f32 (transform, K=256).
// Block 128x128, 4 waves (2x2), wave tile 64x64, K-step 32, 8 steps,
// 2-phase pipeline: issue loads(t+1) -> compute(t) -> ds_write A(t+1) -> barrier.
// FINAL: fuse out = relu(..) @ wfin (per-row dot) instead of storing h.
// ---------------------------------------------------------------------------
template <bool F32A, bool RELU, bool FINAL>
__launch_bounds__(256, 2)
__global__ void gemm_mfma(const void* __restrict__ A0v, const void* __restrict__ A1v,
                          const unsigned short* __restrict__ Wp,
                          const float* __restrict__ bias,
                          const float* __restrict__ wfin,
                          void* __restrict__ outv, int nrows) {
    __shared__ __align__(16) unsigned short Ah[2][8][64][8];
    __shared__ __align__(16) unsigned short Al[2][8][64][8];
    __shared__ __align__(16) unsigned short Bh[2][8][64][8];
    __shared__ __align__(16) unsigned short Bl[2][8][64][8];
    __shared__ float red[FINAL ? 128 : 1][2];

    const int t = threadIdx.x;
    const int lane = t & 63;
    const int w = t >> 6;
    const int wr = w >> 1, wc = w & 1;
    const int blockRow0 = blockIdx.x * 128;

    // staging coordinates for this thread (2 cells: flat = t, t+256)
    int srow[2], skk[2], srt[2], scl[2];
    #pragma unroll
    for (int u = 0; u < 2; ++u) {
        const int flat = t + u * 256;
        srt[u] = flat >> 6;
        scl[u] = flat & 63;
        int row = blockRow0 + srt[u] * 16 + (scl[u] & 15);
        srow[u] = min(row, nrows - 1);
        skk[u] = (scl[u] >> 4) << 3;
    }

    f32x4 acc[4][4];
    #pragma unroll
    for (int i = 0; i < 4; ++i)
        #pragma unroll
        for (int j = 0; j < 4; ++j) acc[i][j] = (f32x4){0.f, 0.f, 0.f, 0.f};

    auto loadA = [&](int step, float (&fv)[2][8]) {
        const int kt = step * 32;
        #pragma unroll
        for (int u = 0; u < 2; ++u) {
            const int kk = kt + skk[u];
            if constexpr (F32A) {
                const float* p = (const float*)A0v + (size_t)srow[u] * 256 + kk;
                float4 f0 = *(const float4*)p;
                float4 f1 = *(const float4*)(p + 4);
                fv[u][0] = f0.x; fv[u][1] = f0.y; fv[u][2] = f0.z; fv[u][3] = f0.w;
                fv[u][4] = f1.x; fv[u][5] = f1.y; fv[u][6] = f1.z; fv[u][7] = f1.w;
            } else {
                const __half* p = (kk < 128)
                    ? (const __half*)A0v + (size_t)srow[u] * HIDDEN + kk
                    : (const __half*)A1v + (size_t)srow[u] * HIDDEN + (kk - 128);
                uint4 raw = *(const uint4*)p;
                __half2* hp = (__half2*)&raw;
                #pragma unroll
                for (int m = 0; m < 4; ++m) {
                    float2 f = __half22float2(hp[m]);
                    fv[u][2 * m]     = f.x;
                    fv[u][2 * m + 1] = f.y;
                }
            }
        }
    };
    auto stageW = [&](int buf, int step) {
        const unsigned short* WpH = Wp + (size_t)step * 4096 + (w * 2) * 512 + lane * 8;
        gload16(WpH,       &Bh[buf][w * 2][0][0]);
        gload16(WpH + 512, &Bh[buf][w * 2 + 1][0][0]);
        gload16(WpH + 32768,       &Bl[buf][w * 2][0][0]);
        gload16(WpH + 32768 + 512, &Bl[buf][w * 2 + 1][0][0]);
    };
    auto writeA = [&](int buf, float (&fv)[2][8]) {
        #pragma unroll
        for (int u = 0; u < 2; ++u) {
            union { short8 v; unsigned short u16[8]; } vh, vl;
            #pragma unroll
            for (int j = 0; j < 8; ++j) {
                unsigned short h = f2bf(fv[u][j]);
                vh.u16[j] = h;
                vl.u16[j] = f2bf(fv[u][j] - bf2f(h));
            }
            *(short8*)&Ah[buf][srt[u]][scl[u]][0] = vh.v;
            *(short8*)&Al[buf][srt[u]][scl[u]][0] = vl.v;
        }
    };
    auto compute = [&](int buf) {
        short8 bh[4], bl[4];
        #pragma unroll
        for (int c4 = 0; c4 < 4; ++c4) {
            bh[c4] = *(const short8*)&Bh[buf][wc * 4 + c4][lane][0];
            bl[c4] = *(const short8*)&Bl[buf][wc * 4 + c4][lane][0];
        }
        #pragma unroll
        for (int r4 = 0; r4 < 4; ++r4) {
            short8 ah = *(const short8*)&Ah[buf][wr * 4 + r4][lane][0];
            short8 al = *(const short8*)&Al[buf][wr * 4 + r4][lane][0];
            #pragma unroll
            for (int c4 = 0; c4 < 4; ++c4) {
                acc[r4][c4] = __builtin_amdgcn_mfma_f32_16x16x32_bf16(ah, bh[c4], acc[r4][c4], 0, 0, 0);
                acc[r4][c4] = __builtin_amdgcn_mfma_f32_16x16x32_bf16(al, bh[c4], acc[r4][c4], 0, 0, 0);
                acc[r4][c4] = __builtin_amdgcn_mfma_f32_16x16x32_bf16(ah, bl[c4], acc[r4][c4], 0, 0, 0);
            }
        }
    };

    // prologue: stage step 0
    {
        float fa[2][8];
        loadA(0, fa);
        stageW(0, 0);
        writeA(0, fa);
    }
    __syncthreads();

    #pragma unroll
    for (int step = 0; step < 8; ++step) {
        const int cur = step & 1;
        float fn[2][8];
        if (step < 7) {
            loadA(step + 1, fn);          // A loads to regs, in flight during compute
            stageW(cur ^ 1, step + 1);    // W DMA to other buffer, drains at barrier
        }
        compute(cur);
        if (step < 7) writeA(cur ^ 1, fn); // A regs had the compute phase to land
        __syncthreads();
    }

    // epilogue
    if constexpr (FINAL) {
        // fused out = relu(acc + bias) @ wfin
        float wf[4], bc[4];
        #pragma unroll
        for (int c4 = 0; c4 < 4; ++c4) {
            const int col = (wc * 4 + c4) * 16 + (lane & 15);
            wf[c4] = wfin[col];
            bc[c4] = bias[col];
        }
        float part[4][4];
        #pragma unroll
        for (int r4 = 0; r4 < 4; ++r4)
            #pragma unroll
            for (int j = 0; j < 4; ++j) {
                float s = 0.f;
                #pragma unroll
                for (int c4 = 0; c4 < 4; ++c4) {
                    float v = acc[r4][c4][j] + bc[c4];
                    if (RELU) v = fmaxf(v, 0.f);
                    s = fmaf(v, wf[c4], s);
                }
                part[r4][j] = s;
            }
        #pragma unroll
        for (int o = 1; o < 16; o <<= 1)
            #pragma unroll
            for (int r4 = 0; r4 < 4; ++r4)
                #pragma unroll
                for (int j = 0; j < 4; ++j)
                    part[r4][j] += __shfl_xor(part[r4][j], o, 64);
        if ((lane & 15) == 0) {
            #pragma unroll
            for (int r4 = 0; r4 < 4; ++r4)
                #pragma unroll
                for (int j = 0; j < 4; ++j) {
                    const int rl = wr * 64 + r4 * 16 + ((lane >> 4) << 2) + j;
                    red[rl][wc] = part[r4][j];
                }
        }
        __syncthreads();
        if (t < 128) {
            const int r = blockRow0 + t;
            if (r < nrows) ((float*)outv)[r] = red[t][0] + red[t][1];
        }
    } else {
        __half* out = (__half*)outv;
        #pragma unroll
        for (int c4 = 0; c4 < 4; ++c4) {
            const int col = (wc * 4 + c4) * 16 + (lane & 15);
            const float bc = bias[col];
            #pragma unroll
            for (int r4 = 0; r4 < 4; ++r4) {
                const int r0 = blockRow0 + (wr * 4 + r4) * 16 + ((lane >> 4) << 2);
                #pragma unroll
                for (int j = 0; j < 4; ++j) {
                    const int r = r0 + j;
                    if (r < nrows) {
                        float v = acc[r4][c4][j] + bc;
                        if (RELU) v = fmaxf(v, 0.f);
                        out[(size_t)r * HIDDEN + col] = __float2half(v);
                    }
                }
            }
        }
    }
}

// ---------------------------------------------------------------------------
// Neighbor mean over fp16 h. One wave per node; 2 edges per wave-load
// (32 lanes x 8B cover one 256B row), 4-deep per half -> 8 rows in flight.
// ---------------------------------------------------------------------------
__global__ void aggregate_h16(const __half* __restrict__ h, const int* __restrict__ offs,
                              const int* __restrict__ deg, const int* __restrict__ csr,
                              __half* __restrict__ agg, int n) {
    const int node = blockIdx.x * 4 + (threadIdx.x >> 6);
    if (node >= n) return;
    const int lane = threadIdx.x & 63;
    const int eh = lane >> 5;           // edge slot (0/1)
    const int c4 = (lane & 31) * 4;     // 4 cols per lane
    const int start = offs[node];
    const int d = deg[node];
    float a0 = 0.f, a1 = 0.f, a2 = 0.f, a3 = 0.f;
    int i = eh;
    for (; i + 6 < d; i += 8) {
        int s[4];
        #pragma unroll
        for (int j = 0; j < 4; ++j) s[j] = csr[start + i + 2 * j];
        #pragma unroll
        for (int j = 0; j < 4; ++j) {
            uint2 raw = *(const uint2*)&h[(size_t)s[j] * HIDDEN + c4];
            float2 f0 = __half22float2(*(__half2*)&raw.x);
            float2 f1 = __half22float2(*(__half2*)&raw.y);
            a0 += f0.x; a1 += f0.y; a2 += f1.x; a3 += f1.y;
        }
    }
    for (; i < d; i += 2) {
        int s0 = csr[start + i];
        uint2 raw = *(const uint2*)&h[(size_t)s0 * HIDDEN + c4];
        float2 f0 = __half22float2(*(__half2*)&raw.x);
        float2 f1 = __half22float2(*(__half2*)&raw.y);
        a0 += f0.x; a1 += f0.y; a2 += f1.x; a3 += f1.y;
    }
    // combine the two edge-slot halves (lane ^ 32)
    a0 += __shfl_xor(a0, 32, 64);
    a1 += __shfl_xor(a1, 32, 64);
    a2 += __shfl_xor(a2, 32, 64);
    a3 += __shfl_xor(a3, 32, 64);
    if (eh == 0) {
        const float inv = 1.0f / (float)max(d, 1);
        __half2 o0 = __floats2half2_rn(a0 * inv, a1 * inv);
        __half2 o1 = __floats2half2_rn(a2 * inv, a3 * inv);
        uint2 raw;
        raw.x = *(unsigned*)&o0;
        raw.y = *(unsigned*)&o1;
        *(uint2*)&agg[(size_t)node * HIDDEN + c4] = raw;
    }
}

// ---------------------------------------------------------------------------
extern "C" void kernel_launch(void* const* d_in, const int* in_sizes, int n_in,
                              void* d_out, int out_size, void* d_ws, size_t ws_size,
                              hipStream_t stream) {
    const float* x     = (const float*)d_in[0];
    const float* W_t   = (const float*)d_in[1];
    const float* b_t   = (const float*)d_in[2];
    const float* W_s0  = (const float*)d_in[3];
    const float* b_s0  = (const float*)d_in[4];
    const float* W_n0  = (const float*)d_in[5];
    const float* W_s1  = (const float*)d_in[6];
    const float* b_s1  = (const float*)d_in[7];
    const float* W_n1  = (const float*)d_in[8];
    const float* W_fin = (const float*)d_in[9];
    const int*   src   = (const int*)d_in[10];
    const int*   dst   = (const int*)d_in[11];
    float* out = (float*)d_out;

    const int N = in_sizes[0] / 256;   // 100000
    const int E = in_sizes[10];        // 1600000

    // workspace carving (256B aligned)
    size_t off_b = 0;
    auto carve = [&](size_t bytes) {
        size_t cur = off_b;
        off_b = (off_b + bytes + 255) & ~(size_t)255;
        return cur;
    };
    char* base = (char*)d_ws;
    int* deg    = (int*)(base + carve((size_t)N * 4));
    int* offs   = (int*)(base + carve((size_t)N * 4));
    int* bsum   = (int*)(base + carve(1024 * 4));
    int* cursor = (int*)(base + carve(NBUCK_MAX * 4));
    int* csr    = (int*)(base + carve((size_t)E * 4));
    unsigned long long* pairs = (unsigned long long*)(base + carve((size_t)E * 8));
    unsigned short* wp_t  = (unsigned short*)(base + carve((size_t)65536 * 2));
    unsigned short* wp_l0 = (unsigned short*)(base + carve((size_t)65536 * 2));
    unsigned short* wp_l1 = (unsigned short*)(base + carve((size_t)65536 * 2));
    __half* hA  = (__half*)(base + carve((size_t)N * HIDDEN * 2));
    __half* hB  = (__half*)(base + carve((size_t)N * HIDDEN * 2));
    __half* agp = (__half*)(base + carve((size_t)N * HIDDEN * 2));
    (void)ws_size; (void)n_in; (void)out_size;

    const int nbScan = (N + 1023) / 1024;      // 98 (<=256 required by scan_bsum)
    const int nBuck  = (N + (1 << BSHIFT) - 1) >> BSHIFT;   // 196

    // --- CSR build ---
    hipLaunchKernelGGL(zero_ints, dim3((N + 255) / 256), dim3(256), 0, stream, deg, N);
    hipLaunchKernelGGL(count_deg, dim3((E + 255) / 256), dim3(256), 0, stream, dst, deg, E);
    hipLaunchKernelGGL(scan_partial, dim3(nbScan), dim3(256), 0, stream, deg, bsum, N);
    hipLaunchKernelGGL(scan_bsum, dim3(1), dim3(256), 0, stream, bsum, nbScan);
    hipLaunchKernelGGL(scan_offsets, dim3(nbScan), dim3(256), 0, stream, deg, bsum, offs, N);
    hipLaunchKernelGGL(init_cursors, dim3(1), dim3(256), 0, stream, offs, cursor, nBuck);
    hipLaunchKernelGGL(partition_pairs, dim3((E + 4095) / 4096), dim3(256), 0, stream,
                       src, dst, cursor, pairs, E);
    hipLaunchKernelGGL(place_csr, dim3(nBuck), dim3(256), 0, stream, pairs, offs, csr, N, E);

    // --- weight packing (48 tiny blocks) ---
    hipLaunchKernelGGL(pack_weights, dim3(48), dim3(256), 0, stream,
                       W_t, W_s0, W_n0, W_s1, W_n1, wp_t, wp_l0, wp_l1);

    const int gemmGrid = (N + 127) / 128;
    const int nodeGrid = (N + 3) / 4;

    // h0 = x @ W_t + b_t  (f32 A path)
    hipLaunchKernelGGL((gemm_mfma<true, false, false>), dim3(gemmGrid), dim3(256), 0, stream,
                       (const void*)x, (const void*)nullptr, wp_t, b_t, (const float*)nullptr,
                       (void*)hA, N);
    // layer 0
    hipLaunchKernelGGL(aggregate_h16, dim3(nodeGrid), dim3(256), 0, stream, hA, offs, deg, csr, agp, N);
    hipLaunchKernelGGL((gemm_mfma<false, true, false>), dim3(gemmGrid), dim3(256), 0, stream,
                       (const void*)hA, (const void*)agp, wp_l0, b_s0, (const float*)nullptr,
                       (void*)hB, N);
    // layer 1 + fused final projection
    hipLaunchKernelGGL(aggregate_h16, dim3(nodeGrid), dim3(256), 0, stream, hB, offs, deg, csr, agp, N);
    hipLaunchKernelGGL((gemm_mfma<false, true, true>), dim3(gemmGrid), dim3(256), 0, stream,
                       (const void*)hB, (const void*)agp, wp_l1, b_s1, W_fin,
                       (void*)out, N);
}